// Round 15
// baseline (1181.958 us; speedup 1.0000x reference)
//
#include <hip/hip_runtime.h>
#include <math.h>

// Problem constants (match reference)
#define NN 200000
#define EE 300000
#define BB 64
#define INV_SQRT_D 0.17677669529663687f

// ---- workspace layout in 4-byte words. Total ≈ 59.19M words = 236.7 MB.
// ws budget is ~256MB-class (252 passed, 329 faulted) -> stay <= 252 MB.
#define OFF_HB   ((size_t)0)                    // [N][64] uint (bf16x2) node features
#define OFF_P0   ((size_t)12800000)             // [N][64] uint: q, then vt_0, then vt_2
#define OFF_P1   ((size_t)25600000)             // [N][64] uint: kt_0 -> kt_1 -> vt_1
#define OFF_AS   ((size_t)38400000)             // [N][64] uint: kt_2 -> As accumulator
#define OFF_S    ((size_t)51200000)             // [3][E][4] f32 scores -> exp (CSR order)
#define OFF_RP   ((size_t)54800000)             // [3][N+1] int rowptr (padded 600016)
#define OFF_CP   ((size_t)55400016)             // [3][E] int2 (src,dst) per CSR position
#define OFF_WF   ((size_t)57200016)             // 14 x [128][128] f32 folded weights
#define OFF_BF   ((size_t)57429392)             // 14 x [128] f32 folded bias
#define OFF_BS   ((size_t)57431184)             // scan block sums 3*128 int
#define OFF_POOL ((size_t)57431568)             // psum [B][256] + pcnt [B][2] (16512)
#define OFF_WT   ((size_t)57448080)             // 16 x [128][64] uint packed W^T
#define OFF_IZ   ((size_t)57579152)             // [N][4] f32 softmax Z (atomic sum)
#define OFF_WIT  ((size_t)58379152)             // [128][52] uint packed Win^T
#define OFF_MX   ((size_t)58385808)             // [N][4] uint enc(max) (atomicMax)

#define SCAN_L   (NN + 1)
#define SCAN_E   8
#define SCAN_EPB (256 * SCAN_E)                          // 2048
#define SCAN_NB  ((SCAN_L + SCAN_EPB - 1) / SCAN_EPB)    // 98

typedef __attribute__((ext_vector_type(8))) short bf16x8;
typedef __attribute__((ext_vector_type(4))) float f32x4;

// Fast gelu: A&S 7.1.26 rational erf approx, |eps| <= 1.5e-7 absolute —
// 2+ orders below bf16 storage rounding of h. ~16 VALU ops vs ~50 for libm erff.
__device__ __forceinline__ float gelu_fast(float v) {
    float x = fabsf(v) * 0.70710678118654752f;
    float t = 1.0f / fmaf(0.3275911f, x, 1.0f);
    float p = fmaf(fmaf(fmaf(fmaf(1.061405429f, t, -1.453152027f), t, 1.421413741f),
                        t, -0.284496736f), t, 0.254829592f) * t;
    float er = 1.0f - p * __expf(-x * x);        // erf(|x|)
    er = copysignf(er, v);
    return 0.5f * v * (1.0f + er);
}
__device__ __forceinline__ float bflo(unsigned u) { return __uint_as_float(u << 16); }
__device__ __forceinline__ float bfhi(unsigned u) { return __uint_as_float(u & 0xffff0000u); }
__device__ __forceinline__ unsigned bfpack(float a, float b) {
    unsigned ua = __float_as_uint(a); ua += 0x7fffu + ((ua >> 16) & 1u);
    unsigned ub = __float_as_uint(b); ub += 0x7fffu + ((ub >> 16) & 1u);
    return (ua >> 16) | (ub & 0xffff0000u);
}
// Monotonic float<->uint encoding for atomicMax on floats.
// enc is strictly increasing in f; enc(any finite) > 0, so zero-init = -inf.
__device__ __forceinline__ unsigned fenc(float f) {
    unsigned u = __float_as_uint(f);
    return (u & 0x80000000u) ? ~u : (u | 0x80000000u);
}
__device__ __forceinline__ float fdec(unsigned e) {
    return __uint_as_float((e & 0x80000000u) ? (e & 0x7fffffffu) : ~e);
}

// ---- fold weights. 14 slots: per layer l: [l*7+0]=q copy, [l*7+1+r]=k@Wk_rel[r],
//      [l*7+4+r]=v@Wv_rel[r].  kqv split order is k|q|v (cols 0/128/256).
__global__ __launch_bounds__(256) void fold_weights(
    const float* __restrict__ Wkqv, const float* __restrict__ bkqv,
    const float* __restrict__ Wk_rel, const float* __restrict__ Wv_rel,
    float* __restrict__ Wf, float* __restrict__ bf)
{
    __shared__ float Wr[4096];
    const int b = blockIdx.x, t = threadIdx.x;
    const int l = b / 7, s = b % 7;
    const float* Wq = Wkqv + (size_t)l * 49152;   // [128][384]
    if (s == 0) {
        for (int i = t; i < 16384; i += 256) {
            int kk = i >> 7, c = i & 127;
            Wf[(size_t)b * 16384 + i] = Wq[kk * 384 + 128 + c];
        }
        if (t < 128) bf[b * 128 + t] = bkqv[l * 384 + 128 + t];
    } else {
        const int side = (s - 1) / 3, r = (s - 1) % 3;
        const int off = side ? 256 : 0;
        const float* Wrel = (side ? Wv_rel : Wk_rel) + (size_t)(l * 3 + r) * 4096;
        for (int i = t; i < 4096; i += 256) Wr[i] = Wrel[i];
        __syncthreads();
        for (int i = t; i < 16384; i += 256) {
            int kk = i >> 7, c = i & 127, hh = c >> 5, f = c & 31;
            const float* wrow = Wq + kk * 384 + off + hh * 32;
            const float* wr = Wr + hh * 1024 + f;
            float sum = 0.f;
#pragma unroll
            for (int d = 0; d < 32; ++d) sum += wrow[d] * wr[d * 32];
            Wf[(size_t)b * 16384 + i] = sum;
        }
        if (t < 128) {
            int hh = t >> 5, f = t & 31;
            float sum = 0.f;
#pragma unroll
            for (int d = 0; d < 32; ++d)
                sum += bkqv[l * 384 + off + hh * 32 + d] * Wr[hh * 1024 + d * 32 + f];
            bf[b * 128 + t] = sum;
        }
    }
}

// ---- pack W -> bf16x2-packed W^T: WT[slot][c][w] = (W[2w][c], W[2w+1][c]) ----
__global__ __launch_bounds__(256) void pack_wt(
    const float* __restrict__ W, unsigned* __restrict__ WT)
{
    const int slot = blockIdx.x, t = threadIdx.x;
    const float* Ws = W + (size_t)slot * 16384;
    unsigned* WTs = WT + (size_t)slot * 8192;
    for (int i = t; i < 8192; i += 256) {
        int c = i >> 6, w = i & 63;
        WTs[i] = bfpack(Ws[(size_t)(2 * w) * 128 + c], Ws[(size_t)(2 * w + 1) * 128 + c]);
    }
}

// ---- pack Win (69x128 f32) -> WinT bf16 [128][52] (K padded to 96 = 48 uints + 4 pad) ----
__global__ __launch_bounds__(256) void pack_win(
    const float* __restrict__ Win, unsigned* __restrict__ WinT)
{
    const int t = threadIdx.x;
    for (int i = t; i < 128 * 52; i += 256) {
        int c = i / 52, u = i - c * 52;
        unsigned v = 0;
        if (u < 34) {
            v = bfpack(Win[(size_t)(2 * u) * 128 + c], Win[(size_t)(2 * u + 1) * 128 + c]);
        } else if (u == 34) {
            v = bfpack(Win[(size_t)68 * 128 + c], 0.f);
        }
        WinT[i] = v;
    }
}

// ===================================================================
// MFMA C layout (16x16x32): col=lane&15, row=(lane>>4)*4+reg. Adjacent
// output cols live in xor-1 neighbor lanes: bias-add in-register,
// shfl_xor(1), pack bf16 pairs directly.
// Row-owning layout (R12): wave w = rows w*16..+15, all 128 cols, B in
// LDS (no write amplification). R13: 512-thread/128-row gemm blocks.
// R14: edge arrays fused to int2 pairs. R15: slot-1 B panel prefetched
// to regs before slot-0 compute (T14 async-stage; R14 PMC: the B1
// staging was the remaining exposed-latency window); out_ln to
// 512-thread/128-row (replicates R13's occupancy gain).
// ===================================================================

// ---- MFMA input projection, 64-row blocks, single barrier ----
// K = 96 padded. B (WinT, 26.6KB) read directly from global (L1/L2-hot).
__global__ __launch_bounds__(256, 4) void input_proj_mfma(
    const float* __restrict__ x, const int* __restrict__ ast,
    const float* __restrict__ emb, const unsigned* __restrict__ WinT,
    const float* __restrict__ bin_, unsigned* __restrict__ h_bf)
{
    __shared__ unsigned Asm[64 * 52];    // 13312 B
    const int t = threadIdx.x;
    const int n0 = blockIdx.x * 64;
    const int w = t >> 6, lane = t & 63;
    const int m = lane & 15, quad = lane >> 4;
    // preload B fragments before staging (hides global latency under stage)
    bf16x8 b0[3], b1[3];
#pragma unroll
    for (int kc = 0; kc < 3; ++kc) {
        const int koff = kc * 16 + quad * 4;
        b0[kc] = *(const bf16x8*)(WinT + (size_t)(32 * w + m) * 52 + koff);
        b1[kc] = *(const bf16x8*)(WinT + (size_t)(32 * w + 16 + m) * 52 + koff);
    }
    // stage A (bf16): cols 0..63 = emb[ast[n]], 64..68 = x[n], 69..95 = 0
    for (int i = t; i < 64 * 32; i += 256) {           // emb part, branch-free
        int row = i >> 5, u = i & 31;
        float2 e = *(const float2*)(emb + (size_t)ast[n0 + row] * 64 + 2 * u);
        Asm[row * 52 + u] = bfpack(e.x, e.y);
    }
    if (t < 192) {                                     // x part: 3 uints per row
        int row = t / 3, j = t - (t / 3) * 3;
        const float* xr = x + (size_t)(n0 + row) * 5;
        float a = (j == 0) ? xr[0] : (j == 1) ? xr[2] : xr[4];
        float b = (j == 0) ? xr[1] : (j == 1) ? xr[3] : 0.f;
        Asm[row * 52 + 32 + j] = bfpack(a, b);
    }
    for (int i = t; i < 64 * 16; i += 256)             // zero pad u=35..50 (reads stop at 47)
        Asm[(i >> 4) * 52 + 35 + (i & 15)] = 0u;
    __syncthreads();
    f32x4 acc[4][2];
#pragma unroll
    for (int rt = 0; rt < 4; ++rt) { acc[rt][0] = (f32x4){0.f,0.f,0.f,0.f}; acc[rt][1] = acc[rt][0]; }
#pragma unroll
    for (int kc = 0; kc < 3; ++kc) {
        const int koff = kc * 16 + quad * 4;
#pragma unroll
        for (int rt = 0; rt < 4; ++rt) {
            bf16x8 a = *(const bf16x8*)&Asm[(rt * 16 + m) * 52 + koff];
            acc[rt][0] = __builtin_amdgcn_mfma_f32_16x16x32_bf16(a, b0[kc], acc[rt][0], 0, 0, 0);
            acc[rt][1] = __builtin_amdgcn_mfma_f32_16x16x32_bf16(a, b1[kc], acc[rt][1], 0, 0, 0);
        }
    }
    const float bv0 = bin_[32 * w + m], bv1 = bin_[32 * w + 16 + m];
    const int ub = 16 * w + 8 * (m & 1) + (m >> 1);
#pragma unroll
    for (int rt = 0; rt < 4; ++rt)
#pragma unroll
        for (int r = 0; r < 4; ++r) {
            float v0 = acc[rt][0][r] + bv0;
            float v1 = acc[rt][1][r] + bv1;
            float nv0 = __shfl_xor(v0, 1);
            float nv1 = __shfl_xor(v1, 1);
            unsigned pk = (m & 1) ? bfpack(nv1, v1) : bfpack(v0, nv0);
            h_bf[(size_t)(n0 + rt * 16 + quad * 4 + r) * 64 + ub] = pk;
        }
}

// ---- CSR build: histogram -> scan -> scatter ----
__global__ __launch_bounds__(256) void csr_hist(
    const int* __restrict__ ei0, const int* __restrict__ ei1, const int* __restrict__ ei2,
    int* __restrict__ rp)
{
    int idx = blockIdx.x * 256 + threadIdx.x;
    if (idx >= 3 * EE) return;
    int r = idx / EE, e = idx - r * EE;
    const int* ei = (r == 0) ? ei0 : ((r == 1) ? ei1 : ei2);
    atomicAdd(&rp[r * SCAN_L + ei[EE + e] + 1], 1);
}

__global__ __launch_bounds__(256) void scan1(int* __restrict__ rp, int* __restrict__ bs)
{
    __shared__ int ts[256];
    const int r = blockIdx.y;
    int* a = rp + (size_t)r * SCAN_L;
    const int base = blockIdx.x * SCAN_EPB + threadIdx.x * SCAN_E;
    int v[SCAN_E];
    int tot = 0;
#pragma unroll
    for (int j = 0; j < SCAN_E; ++j) {
        int idx = base + j;
        v[j] = (idx < SCAN_L) ? a[idx] : 0;
        tot += v[j];
    }
    ts[threadIdx.x] = tot;
    __syncthreads();
    for (int st = 1; st < 256; st <<= 1) {
        int add = (threadIdx.x >= st) ? ts[threadIdx.x - st] : 0;
        __syncthreads();
        ts[threadIdx.x] += add;
        __syncthreads();
    }
    int run = ts[threadIdx.x] - tot;
#pragma unroll
    for (int j = 0; j < SCAN_E; ++j) {
        run += v[j];
        int idx = base + j;
        if (idx < SCAN_L) a[idx] = run;
    }
    if (threadIdx.x == 255) bs[r * 128 + blockIdx.x] = ts[255];
}

__global__ __launch_bounds__(128) void scan2(int* __restrict__ bs)
{
    __shared__ int ts[128];
    const int r = blockIdx.x, t = threadIdx.x;
    int v = (t < SCAN_NB) ? bs[r * 128 + t] : 0;
    ts[t] = v;
    __syncthreads();
    for (int st = 1; st < 128; st <<= 1) {
        int add = (t >= st) ? ts[t - st] : 0;
        __syncthreads();
        ts[t] += add;
        __syncthreads();
    }
    bs[r * 128 + t] = ts[t];
}

__global__ __launch_bounds__(256) void scan3(int* __restrict__ rp, const int* __restrict__ bs)
{
    const int r = blockIdx.y;
    if (blockIdx.x == 0) return;
    const int off = bs[r * 128 + blockIdx.x - 1];
    const int base = blockIdx.x * SCAN_EPB + threadIdx.x * SCAN_E;
    int* a = rp + (size_t)r * SCAN_L;
#pragma unroll
    for (int j = 0; j < SCAN_E; ++j) {
        int idx = base + j;
        if (idx < SCAN_L) a[idx] += off;
    }
}

// ---- scatter: ONE int2 (src,dst) 8B store per edge (R14) ----
__global__ __launch_bounds__(256) void csr_scatter(
    const int* __restrict__ ei0, const int* __restrict__ ei1, const int* __restrict__ ei2,
    const int* __restrict__ rp, int* __restrict__ fill, int2* __restrict__ cpair)
{
    int idx = blockIdx.x * 256 + threadIdx.x;
    if (idx >= 3 * EE) return;
    int r = idx / EE, e = idx - r * EE;
    const int* ei = (r == 0) ? ei0 : ((r == 1) ? ei1 : ei2);
    int src = ei[e], dst = ei[EE + e];
    int pos = rp[r * SCAN_L + dst] + atomicAdd(&fill[r * NN + dst], 1);
    cpair[r * EE + pos] = make_int2(src, dst);
}

// ---- row-owning GEMM core: wave w = rows w*16..w*16+15, all 128 cols. ----
__device__ __forceinline__ void gemm_row_slot(
    const unsigned* Bsm, const bf16x8 a[4],
    int n0, int w, int m, int quad,
    const float* __restrict__ bias, unsigned* __restrict__ outp)
{
    float bo[8];
#pragma unroll
    for (int ct = 0; ct < 8; ++ct) bo[ct] = bias[ct * 16 + m];
    f32x4 acc[8];
#pragma unroll
    for (int ct = 0; ct < 8; ++ct) {
        acc[ct] = (f32x4){0.f, 0.f, 0.f, 0.f};
#pragma unroll
        for (int kc = 0; kc < 4; ++kc) {
            bf16x8 b = *(const bf16x8*)&Bsm[(ct * 16 + m) * 68 + kc * 16 + quad * 4];
            acc[ct] = __builtin_amdgcn_mfma_f32_16x16x32_bf16(a[kc], b, acc[ct], 0, 0, 0);
        }
    }
#pragma unroll
    for (int r = 0; r < 4; ++r) {
        const size_t n = (size_t)(n0 + w * 16 + quad * 4 + r);
        if (n < NN) {
#pragma unroll
            for (int cp = 0; cp < 4; ++cp) {
                float v0 = acc[2 * cp][r]     + bo[2 * cp];
                float v1 = acc[2 * cp + 1][r] + bo[2 * cp + 1];
                float nv0 = __shfl_xor(v0, 1);
                float nv1 = __shfl_xor(v1, 1);
                unsigned pk = (m & 1) ? bfpack(nv1, v1) : bfpack(v0, nv0);
                outp[n * 64 + cp * 16 + 8 * (m & 1) + (m >> 1)] = pk;
            }
        } else {
            // keep shuffles wave-uniform for inactive rows
#pragma unroll
            for (int cp = 0; cp < 4; ++cp) {
                float v0 = acc[2 * cp][r], v1 = acc[2 * cp + 1][r];
                (void)__shfl_xor(v0, 1); (void)__shfl_xor(v1, 1);
            }
        }
    }
}

// ---- 1-slot 128-row GEMM, row-owning, 512 threads (R13) ----
__global__ __launch_bounds__(512, 4) void gemm_mfma(
    const unsigned* __restrict__ in_bf, const unsigned* __restrict__ WT,
    const float* __restrict__ bias, unsigned* __restrict__ outp)
{
    __shared__ unsigned Asm[128 * 68];   // 34816 B
    __shared__ unsigned Bsm[128 * 68];   // 34816 B
    const int t = threadIdx.x;
    const int n0 = blockIdx.x * 128;
    const int w = t >> 6, lane = t & 63;
    const int m = lane & 15, quad = lane >> 4;
    for (int i = t; i < 128 * 16; i += 512) {
        int row = i >> 4, q4 = i & 15;
        size_t n = (size_t)(n0 + row); if (n >= NN) n = NN - 1;
        uint4 v = *(const uint4*)(in_bf + n * 64 + q4 * 4);
        *(uint4*)&Asm[row * 68 + q4 * 4] = v;
    }
    for (int i = t; i < 128 * 16; i += 512) {
        int row = i >> 4, q4 = i & 15;
        uint4 v = *(const uint4*)(WT + (size_t)row * 64 + q4 * 4);
        *(uint4*)&Bsm[row * 68 + q4 * 4] = v;
    }
    __syncthreads();
    bf16x8 a[4];
#pragma unroll
    for (int kc = 0; kc < 4; ++kc)
        a[kc] = *(const bf16x8*)&Asm[(w * 16 + m) * 68 + kc * 16 + quad * 4];
    gemm_row_slot(Bsm, a, n0, w, m, quad, bias, outp);
}

// ---- 2-slot 128-row GEMM, 512 threads. R15: B1 panel prefetched into
//      registers BEFORE slot-0 compute (T14) — its global latency hides
//      under the MFMA phase; post-slot0 only a ds_write remains. ----
__global__ __launch_bounds__(512, 4) void gemm_mfma2(
    const unsigned* __restrict__ in_bf,
    const unsigned* __restrict__ WT0, const float* __restrict__ bias0,
    unsigned* __restrict__ out0,
    const unsigned* __restrict__ WT1, const float* __restrict__ bias1,
    unsigned* __restrict__ out1)
{
    __shared__ unsigned Asm[128 * 68];
    __shared__ unsigned Bsm[128 * 68];
    const int t = threadIdx.x;
    const int n0 = blockIdx.x * 128;
    const int w = t >> 6, lane = t & 63;
    const int m = lane & 15, quad = lane >> 4;
    for (int i = t; i < 128 * 16; i += 512) {
        int row = i >> 4, q4 = i & 15;
        size_t n = (size_t)(n0 + row); if (n >= NN) n = NN - 1;
        uint4 v = *(const uint4*)(in_bf + n * 64 + q4 * 4);
        *(uint4*)&Asm[row * 68 + q4 * 4] = v;
    }
    for (int i = t; i < 128 * 16; i += 512) {
        int row = i >> 4, q4 = i & 15;
        uint4 v = *(const uint4*)(WT0 + (size_t)row * 64 + q4 * 4);
        *(uint4*)&Bsm[row * 68 + q4 * 4] = v;
    }
    // prefetch B1 into registers (in flight across slot-0 compute)
    uint4 pb[4];
#pragma unroll
    for (int j = 0; j < 4; ++j) {
        int i = t + j * 512;
        int row = i >> 4, q4 = i & 15;
        pb[j] = *(const uint4*)(WT1 + (size_t)row * 64 + q4 * 4);
    }
    __syncthreads();
    bf16x8 a[4];
#pragma unroll
    for (int kc = 0; kc < 4; ++kc)
        a[kc] = *(const bf16x8*)&Asm[(w * 16 + m) * 68 + kc * 16 + quad * 4];
    gemm_row_slot(Bsm, a, n0, w, m, quad, bias0, out0);
    __syncthreads();                       // all waves done reading B0
#pragma unroll
    for (int j = 0; j < 4; ++j) {
        int i = t + j * 512;
        int row = i >> 4, q4 = i & 15;
        *(uint4*)&Bsm[row * 68 + q4 * 4] = pb[j];
    }
    __syncthreads();
    gemm_row_slot(Bsm, a, n0, w, m, quad, bias1, out1);
}

// ---- edge scores in CSR position order; also atomicMax the per-(dst,head)
//      running max. (src,dst) from one int2 load (R14). ----
__global__ __launch_bounds__(256) void edge_scores_csr(
    const unsigned* __restrict__ q_bf, const unsigned* __restrict__ k_bf,
    const int2* __restrict__ cpair,
    const float* __restrict__ p4, float* __restrict__ s_out,
    unsigned* __restrict__ mxi)
{
    int idx = blockIdx.x * 256 + threadIdx.x;
    if (idx >= EE * 4) return;
    int p = idx >> 2, hh = idx & 3;
    int2 pr = cpair[p];
    int src = pr.x, dst = pr.y;
    const uint4* qp = (const uint4*)(q_bf + (size_t)dst * 64 + hh * 16);
    const uint4* kp = (const uint4*)(k_bf + (size_t)src * 64 + hh * 16);
    float sum = 0.f;
#pragma unroll
    for (int i = 0; i < 4; ++i) {
        uint4 qa = qp[i], ka = kp[i];
        sum += bflo(qa.x) * bflo(ka.x) + bfhi(qa.x) * bfhi(ka.x);
        sum += bflo(qa.y) * bflo(ka.y) + bfhi(qa.y) * bfhi(ka.y);
        sum += bflo(qa.z) * bflo(ka.z) + bfhi(qa.z) * bfhi(ka.z);
        sum += bflo(qa.w) * bflo(ka.w) + bfhi(qa.w) * bfhi(ka.w);
    }
    float s = sum * p4[hh] * INV_SQRT_D;
    s_out[(size_t)p * 4 + hh] = s;
    atomicMax(&mxi[(size_t)dst * 4 + hh], fenc(s));
}

// ---- edge_exp_z: one edge-parallel pass after all 3 relations' scores:
//      e = exp(s - m[dst]); overwrite s with e; atomicAdd Z[dst]. ----
__global__ __launch_bounds__(256) void edge_exp_z(
    float* __restrict__ s, const int2* __restrict__ cpair,
    const unsigned* __restrict__ mxi, float* __restrict__ Z)
{
    int idx = blockIdx.x * 256 + threadIdx.x;
    if (idx >= 3 * EE * 4) return;
    int p = idx >> 2, hh = idx & 3;
    int dst = cpair[p].y;
    float m = fdec(mxi[(size_t)dst * 4 + hh]);
    float e = __expf(s[idx] - m);
    s[idx] = e;
    atomicAdd(&Z[(size_t)dst * 4 + hh], e);
}

// ---- agg_reg: 16-lane-group-per-dst register aggregation (4 dsts/wave).
//      Lane sl=lane&15 owns uint4 = cols 8*sl..8*sl+7 (one head: hh=sl>>2).
//      src from cpair[].x (wave-uniform per group -> broadcast load). ----
template<int NREL, int FIRST>
__global__ __launch_bounds__(256, 8) void agg_reg(
    const unsigned* __restrict__ pA, const unsigned* __restrict__ pB,
    const float* __restrict__ s, const int* __restrict__ rp,
    const int2* __restrict__ cpair, int ra, int rb,
    const float* __restrict__ Z, unsigned* __restrict__ As_g)
{
    const int lane = threadIdx.x & 63;
    const int sl = lane & 15;                 // sub-lane within dst group
    const int dst = blockIdx.x * 16 + (threadIdx.x >> 6) * 4 + (lane >> 4);
    const int hh = sl >> 2;                   // head of this lane's 8 cols
    float zz = Z[(size_t)dst * 4 + hh];
    float iz = 1.f / (zz + 1e-16f);
    float a0 = 0.f, a1 = 0.f, a2 = 0.f, a3 = 0.f;
    float a4 = 0.f, a5 = 0.f, a6 = 0.f, a7 = 0.f;
#pragma unroll
    for (int q = 0; q < NREL; ++q) {
        const unsigned* pl = q ? pB : pA;
        const int r = q ? rb : ra;
        const int beg = rp[r * SCAN_L + dst];
        const int end = rp[r * SCAN_L + dst + 1];
        int p = beg;
        for (; p + 1 < end; p += 2) {
            int s0 = cpair[r * EE + p].x;
            float al0 = s[((size_t)r * EE + p) * 4 + hh];
            int s1 = cpair[r * EE + p + 1].x;
            float al1 = s[((size_t)r * EE + p + 1) * 4 + hh];
            uint4 v0 = *(const uint4*)(pl + (size_t)s0 * 64 + sl * 4);
            uint4 v1 = *(const uint4*)(pl + (size_t)s1 * 64 + sl * 4);
            a0 += al0 * bflo(v0.x) + al1 * bflo(v1.x);
            a1 += al0 * bfhi(v0.x) + al1 * bfhi(v1.x);
            a2 += al0 * bflo(v0.y) + al1 * bflo(v1.y);
            a3 += al0 * bfhi(v0.y) + al1 * bfhi(v1.y);
            a4 += al0 * bflo(v0.z) + al1 * bflo(v1.z);
            a5 += al0 * bfhi(v0.z) + al1 * bfhi(v1.z);
            a6 += al0 * bflo(v0.w) + al1 * bflo(v1.w);
            a7 += al0 * bfhi(v0.w) + al1 * bfhi(v1.w);
        }
        if (p < end) {
            int s0 = cpair[r * EE + p].x;
            float al0 = s[((size_t)r * EE + p) * 4 + hh];
            uint4 v0 = *(const uint4*)(pl + (size_t)s0 * 64 + sl * 4);
            a0 += al0 * bflo(v0.x); a1 += al0 * bfhi(v0.x);
            a2 += al0 * bflo(v0.y); a3 += al0 * bfhi(v0.y);
            a4 += al0 * bflo(v0.z); a5 += al0 * bfhi(v0.z);
            a6 += al0 * bflo(v0.w); a7 += al0 * bfhi(v0.w);
        }
    }
    a0 *= iz; a1 *= iz; a2 *= iz; a3 *= iz;
    a4 *= iz; a5 *= iz; a6 *= iz; a7 *= iz;
    unsigned* op = As_g + (size_t)dst * 64 + sl * 4;
    if (FIRST) {
        uint4 o;
        o.x = bfpack(a0, a1); o.y = bfpack(a2, a3);
        o.z = bfpack(a4, a5); o.w = bfpack(a6, a7);
        *(uint4*)op = o;
    } else {
        uint4 old = *(const uint4*)op;
        uint4 o;
        o.x = bfpack(gelu_fast(bflo(old.x) + a0), gelu_fast(bfhi(old.x) + a1));
        o.y = bfpack(gelu_fast(bflo(old.y) + a2), gelu_fast(bfhi(old.y) + a3));
        o.z = bfpack(gelu_fast(bflo(old.z) + a4), gelu_fast(bfhi(old.z) + a5));
        o.w = bfpack(gelu_fast(bflo(old.w) + a6), gelu_fast(bfhi(old.w) + a7));
        *(uint4*)op = o;
    }
}

// ---- out_ln: As(pre-gelu'd) @ Wout + bout -> skip -> LN -> h ----
// R9: wave owns 16 complete rows x 128 cols; one 16-lane butterfly per row.
// R11: B panel in LDS. R15: 512-thread/128-row blocks (R13 occupancy gain),
// tail-guarded (clamped loads; store guard uniform per 16-lane group).
__global__ __launch_bounds__(512, 4) void out_ln(
    const unsigned* __restrict__ As_g, unsigned* __restrict__ h_bf,
    const unsigned* __restrict__ WT, const float* __restrict__ bout,
    const float* __restrict__ skipp, const float* __restrict__ lg,
    const float* __restrict__ lb)
{
    __shared__ unsigned Asm[128 * 68];   // 34816 B
    __shared__ unsigned Bsm[128 * 68];   // 34816 B
    const int t = threadIdx.x;
    const int n0 = blockIdx.x * 128;
    const int w = t >> 6, lane = t & 63;
    const int m = lane & 15, quad = lane >> 4;
    // stage A (pre-gelu'd As) and B (WT slot) to LDS, coalesced
    for (int i = t; i < 128 * 16; i += 512) {
        int row = i >> 4, q4 = i & 15;
        size_t n = (size_t)(n0 + row); if (n >= NN) n = NN - 1;
        uint4 v = *(const uint4*)(As_g + n * 64 + q4 * 4);
        *(uint4*)&Asm[row * 68 + q4 * 4] = v;
    }
    for (int i = t; i < 128 * 16; i += 512) {
        int row = i >> 4, q4 = i & 15;
        uint4 v = *(const uint4*)(WT + (size_t)row * 64 + q4 * 4);
        *(uint4*)&Bsm[row * 68 + q4 * 4] = v;
    }
    // per-col constants for this lane's 8 col-tiles (col = ct*16+m)
    float bo[8], g8[8], lb8[8];
#pragma unroll
    for (int ct = 0; ct < 8; ++ct) {
        bo[ct]  = bout[ct * 16 + m];
        g8[ct]  = lg[ct * 16 + m];
        lb8[ct] = lb[ct * 16 + m];
    }
    const float alpha = 1.f / (1.f + expf(-skipp[0]));
    const float om = 1.f - alpha;
    __syncthreads();
    // lane's A row = w*16+m (4 b128 LDS reads)
    bf16x8 a[4];
#pragma unroll
    for (int kc = 0; kc < 4; ++kc)
        a[kc] = *(const bf16x8*)&Asm[(w * 16 + m) * 68 + kc * 16 + quad * 4];
    // MFMA over 8 col-tiles; B from LDS
    f32x4 acc[8];
#pragma unroll
    for (int ct = 0; ct < 8; ++ct) {
        acc[ct] = (f32x4){0.f, 0.f, 0.f, 0.f};
#pragma unroll
        for (int kc = 0; kc < 4; ++kc) {
            bf16x8 b = *(const bf16x8*)&Bsm[(ct * 16 + m) * 68 + kc * 16 + quad * 4];
            acc[ct] = __builtin_amdgcn_mfma_f32_16x16x32_bf16(a[kc], b, acc[ct], 0, 0, 0);
        }
    }
    // o = alpha*(C+bout) + (1-alpha)*h_old; lane's output rows: w*16+quad*4+r
    const bool hi = (m & 1);
#pragma unroll
    for (int ct = 0; ct < 8; ++ct)
#pragma unroll
        for (int r = 0; r < 4; ++r) {
            size_t n = (size_t)(n0 + w * 16 + quad * 4 + r);
            if (n >= NN) n = NN - 1;            // clamped read (unused rows)
            unsigned hu = h_bf[n * 64 + ct * 8 + (m >> 1)];
            float p = hi ? bfhi(hu) : bflo(hu);
            acc[ct][r] = alpha * (acc[ct][r] + bo[ct]) + om * p;
        }
    // LN + pack + store, fully within the 16-lane group (n uniform per group)
#pragma unroll
    for (int r = 0; r < 4; ++r) {
        float po = 0.f, pq = 0.f;
#pragma unroll
        for (int ct = 0; ct < 8; ++ct) {
            float o = acc[ct][r];
            po += o;
            pq += o * o;
        }
#pragma unroll
        for (int sshf = 1; sshf < 16; sshf <<= 1) {
            po += __shfl_xor(po, sshf);
            pq += __shfl_xor(pq, sshf);
        }
        float mu = po * (1.f / 128.f);
        float var = pq * (1.f / 128.f) - mu * mu;
        float rs = rsqrtf(var + 1e-5f);
        const size_t n = (size_t)(n0 + w * 16 + quad * 4 + r);
        if (n < NN) {
#pragma unroll
            for (int cp = 0; cp < 4; ++cp) {
                float v0 = (acc[2 * cp][r]     - mu) * rs * g8[2 * cp]     + lb8[2 * cp];
                float v1 = (acc[2 * cp + 1][r] - mu) * rs * g8[2 * cp + 1] + lb8[2 * cp + 1];
                float nv0 = __shfl_xor(v0, 1);
                float nv1 = __shfl_xor(v1, 1);
                unsigned pk = (m & 1) ? bfpack(nv1, v1) : bfpack(v0, nv0);
                h_bf[n * 64 + cp * 16 + 8 * (m & 1) + (m >> 1)] = pk;
            }
        } else {
#pragma unroll
            for (int cp = 0; cp < 4; ++cp) {
                float v0 = acc[2 * cp][r], v1 = acc[2 * cp + 1][r];
                (void)__shfl_xor(v0, 1); (void)__shfl_xor(v1, 1);
            }
        }
    }
}

// ---- pool_graph: 8 chunks/graph; single-graph blocks -> register accumulate,
//      LDS reduce, 260 global atomics per block ----
__global__ __launch_bounds__(256) void pool_graph(
    const unsigned* __restrict__ h_bf, const float* __restrict__ x,
    const int* __restrict__ batch, float* __restrict__ psum, float* __restrict__ pcnt)
{
    __shared__ float ls[258];
    const int b = blockIdx.x >> 3;
    const int chunk = blockIdx.x & 7;
    const int t = threadIdx.x;
    int lo = 0, hi = NN;
    while (lo < hi) { int mid = (lo + hi) >> 1; if (batch[mid] < b) lo = mid + 1; else hi = mid; }
    const int start = lo;
    lo = 0; hi = NN;
    while (lo < hi) { int mid = (lo + hi) >> 1; if (batch[mid] < b + 1) lo = mid + 1; else hi = mid; }
    const int end = lo;
    const int len = end - start;
    const int c0 = start + (int)(((long long)len * chunk) >> 3);
    const int c1 = start + (int)(((long long)len * (chunk + 1)) >> 3);
    for (int i = t; i < 258; i += 256) ls[i] = 0.f;
    __syncthreads();
    const int c2 = t & 63;
    const int rs = t >> 6;
    float sw0 = 0.f, sw1 = 0.f, sn0 = 0.f, sn1 = 0.f, cw = 0.f, cn = 0.f;
    for (int n = c0 + rs; n < c1; n += 4) {
        float w = (x[(size_t)n * 5 + 1] > 0.f) ? 1.f : 0.f;
        unsigned u = h_bf[(size_t)n * 64 + c2];
        float h0 = bflo(u), h1 = bfhi(u);
        sw0 += w * h0; sw1 += w * h1;
        sn0 += (1.f - w) * h0; sn1 += (1.f - w) * h1;
        cw += w; cn += 1.f - w;
    }
    atomicAdd(&ls[c2 * 4 + 0], sw0);
    atomicAdd(&ls[c2 * 4 + 1], sw1);
    atomicAdd(&ls[c2 * 4 + 2], sn0);
    atomicAdd(&ls[c2 * 4 + 3], sn1);
    if (c2 == 0) { atomicAdd(&ls[256], cw); atomicAdd(&ls[257], cn); }
    __syncthreads();
    if (t < 64) {
        atomicAdd(&psum[b * 256 + 2 * t],       ls[t * 4 + 0]);
        atomicAdd(&psum[b * 256 + 2 * t + 1],   ls[t * 4 + 1]);
        atomicAdd(&psum[b * 256 + 128 + 2 * t],     ls[t * 4 + 2]);
        atomicAdd(&psum[b * 256 + 128 + 2 * t + 1], ls[t * 4 + 3]);
    } else if (t == 64) {
        atomicAdd(&pcnt[b * 2], ls[256]);
        atomicAdd(&pcnt[b * 2 + 1], ls[257]);
    }
}

// ---------------- MLP head (pool finalize fused) ----------------
__global__ __launch_bounds__(256) void head_kernel(
    const float* __restrict__ psum, const float* __restrict__ pcnt,
    const float* __restrict__ task,
    const float* __restrict__ Wtf, const float* __restrict__ btf,
    const float* __restrict__ Wc1, const float* __restrict__ bc1,
    const float* __restrict__ Wc2, const float* __restrict__ bc2,
    float* __restrict__ out)
{
    __shared__ float in_s[640];
    __shared__ float ge_s[256];
    __shared__ float hc_s[64];
    const int b = blockIdx.x, t = threadIdx.x;
    if (t < 256) {
        float cnt = pcnt[b * 2 + (t >> 7)];
        float sv = psum[b * 256 + t];
        in_s[t] = (cnt > 0.f) ? sv / fmaxf(cnt, 1.f) : 0.f;
    }
    for (int i = t; i < 384; i += 256) in_s[256 + i] = task[b * 384 + i];
    __syncthreads();
    float acc = btf[t];
    for (int i = 0; i < 640; ++i) acc += in_s[i] * Wtf[i * 256 + t];
    ge_s[t] = fmaxf(acc, 0.f);
    __syncthreads();
    if (t < 64) {
        float a2 = bc1[t];
        for (int i = 0; i < 256; ++i) a2 += ge_s[i] * Wc1[i * 64 + t];
        hc_s[t] = fmaxf(a2, 0.f);
    }
    __syncthreads();
    if (t < 64) {
        float v = hc_s[t] * Wc2[t];
#pragma unroll
        for (int off = 32; off >= 1; off >>= 1) v += __shfl_down(v, off);
        if (t == 0) out[b] = v + bc2[0];
    }
}

__global__ __launch_bounds__(256) void zero_kernel(float4* __restrict__ p, int count4)
{
    int i = blockIdx.x * 256 + threadIdx.x;
    if (i < count4) p[i] = make_float4(0.f, 0.f, 0.f, 0.f);
}

extern "C" void kernel_launch(void* const* d_in, const int* in_sizes, int n_in,
                              void* d_out, int out_size, void* d_ws, size_t ws_size,
                              hipStream_t stream)
{
    const float* x      = (const float*)d_in[0];
    const int*   ast    = (const int*)d_in[1];
    const int*   batch  = (const int*)d_in[2];
    const int*   ei[3]  = {(const int*)d_in[3], (const int*)d_in[4], (const int*)d_in[5]};
    const float* task   = (const float*)d_in[6];
    const float* emb    = (const float*)d_in[7];
    const float* Win    = (const float*)d_in[8];
    const float* bin_   = (const float*)d_in[9];
    const float* Wkqv   = (const float*)d_in[10];
    const float* bkqv   = (const float*)d_in[11];
    const float* Wk_rel = (const float*)d_in[12];
    const float* Wv_rel = (const float*)d_in[13];
    const float* p_rel  = (const float*)d_in[14];
    const float* Wout   = (const float*)d_in[15];
    const float* bout   = (const float*)d_in[16];
    const float* skip   = (const float*)d_in[17];
    const float* ln_g   = (const float*)d_in[18];
    const float* ln_b   = (const float*)d_in[19];
    const float* Wtf    = (const float*)d_in[20];
    const float* btf    = (const float*)d_in[21];
    const float* Wc1    = (const float*)d_in[22];
    const float* bc1    = (const float*)d_in[23];
    const float* Wc2    = (const float*)d_in[24];
    const float* bc2    = (const float*)d_in[25];
    float* out = (float*)d_out;
    float* ws  = (float*)d_ws;

    unsigned* hB   = (unsigned*)(ws + OFF_HB);
    unsigned* P0   = (unsigned*)(ws + OFF_P0);   // q -> vt_0 -> vt_2
    unsigned* P1   = (unsigned*)(ws + OFF_P1);   // kt_0 -> kt_1 -> vt_1
    unsigned* AS   = (unsigned*)(ws + OFF_AS);   // kt_2 -> As accumulator
    float*    sbuf = ws + OFF_S;
    int*      rp   = (int*)(ws + OFF_RP);
    int2*     cpair= (int2*)(ws + OFF_CP);
    int*      fill = (int*)(ws + OFF_P0);        // aliases P0 during CSR build only
    float*    Wf   = ws + OFF_WF;
    float*    bf   = ws + OFF_BF;
    int*      bs   = (int*)(ws + OFF_BS);
    float*    psum = ws + OFF_POOL;
    float*    pcnt = psum + (size_t)BB * 256;
    unsigned* WT   = (unsigned*)(ws + OFF_WT);   // 14 gemm slots + 2 Wout slots
    float*    Zbuf = ws + OFF_IZ;                // [N][4] softmax Z (atomic sum)
    unsigned* WinT = (unsigned*)(ws + OFF_WIT);
    unsigned* mxi  = (unsigned*)(ws + OFF_MX);   // [N][4] enc(max)

    fold_weights<<<14, 256, 0, stream>>>(Wkqv, bkqv, Wk_rel, Wv_rel, Wf, bf);
    pack_wt<<<14, 256, 0, stream>>>(Wf, WT);
    pack_wt<<<2, 256, 0, stream>>>(Wout, WT + (size_t)14 * 8192);
    pack_win<<<1, 256, 0, stream>>>(Win, WinT);
    input_proj_mfma<<<NN / 64, 256, 0, stream>>>(x, ast, emb, WinT, bin_, hB);

    zero_kernel<<<(600016 / 4 + 255) / 256, 256, 0, stream>>>((float4*)rp, 600016 / 4);
    zero_kernel<<<(600000 / 4 + 255) / 256, 256, 0, stream>>>((float4*)fill, 600000 / 4);
    csr_hist<<<(3 * EE + 255) / 256, 256, 0, stream>>>(ei[0], ei[1], ei[2], rp);
    scan1<<<dim3(SCAN_NB, 3), 256, 0, stream>>>(rp, bs);
    scan2<<<3, 128, 0, stream>>>(bs);
    scan3<<<dim3(SCAN_NB, 3), 256, 0, stream>>>(rp, bs);
    csr_scatter<<<(3 * EE + 255) / 256, 256, 0, stream>>>(
        ei[0], ei[1], ei[2], rp, fill, cpair);

    const int GG = (NN + 127) / 128;   // 1563 (tail-guarded)
    for (int l = 0; l < 2; ++l) {
        const size_t ls = (size_t)l * 7;   // slots: 0=q, 1..3=kt_r, 4..6=vt_r
        // zero-init softmax stats (enc(-inf) < 0+; Z = 0)
        zero_kernel<<<(800000 / 4 + 255) / 256, 256, 0, stream>>>((float4*)mxi, 800000 / 4);
        zero_kernel<<<(800000 / 4 + 255) / 256, 256, 0, stream>>>((float4*)Zbuf, 800000 / 4);
        // q -> P0, kt_0 -> P1
        gemm_mfma2<<<GG, 512, 0, stream>>>(
            hB, WT + ls * 8192, bf + ls * 128, P0,
            WT + (ls + 1) * 8192, bf + (ls + 1) * 128, P1);
        edge_scores_csr<<<(EE * 4 + 255) / 256, 256, 0, stream>>>(
            P0, P1, cpair, p_rel + (size_t)l * 12, sbuf, mxi);
        // kt_1 -> P1 (kt_0 consumed), kt_2 -> AS (dead until agg)
        gemm_mfma2<<<GG, 512, 0, stream>>>(
            hB, WT + (ls + 2) * 8192, bf + (ls + 2) * 128, P1,
            WT + (ls + 3) * 8192, bf + (ls + 3) * 128, AS);
        edge_scores_csr<<<(EE * 4 + 255) / 256, 256, 0, stream>>>(
            P0, P1, cpair + (size_t)EE,
            p_rel + (size_t)(l * 3 + 1) * 4, sbuf + (size_t)EE * 4, mxi);
        edge_scores_csr<<<(EE * 4 + 255) / 256, 256, 0, stream>>>(
            P0, AS, cpair + (size_t)2 * EE,
            p_rel + (size_t)(l * 3 + 2) * 4, sbuf + (size_t)2 * EE * 4, mxi);
        // edge-parallel exp + Z accumulation (all 3 relations at once)
        edge_exp_z<<<(3 * EE * 4 + 255) / 256, 256, 0, stream>>>(sbuf, cpair, mxi, Zbuf);
        // vt_0 -> P0 (q dead), vt_1 -> P1
        gemm_mfma2<<<GG, 512, 0, stream>>>(
            hB, WT + (ls + 4) * 8192, bf + (ls + 4) * 128, P0,
            WT + (ls + 5) * 8192, bf + (ls + 5) * 128, P1);
        agg_reg<2, 1><<<NN / 16, 256, 0, stream>>>(P0, P1, sbuf, rp, cpair, 0, 1, Zbuf, AS);
        gemm_mfma<<<GG, 512, 0, stream>>>(hB, WT + (ls + 6) * 8192, bf + (ls + 6) * 128, P0);
        agg_reg<1, 0><<<NN / 16, 256, 0, stream>>>(P0, P0, sbuf, rp, cpair, 2, 2, Zbuf, AS);
        out_ln<<<GG, 512, 0, stream>>>(
            AS, hB, WT + (size_t)(14 + l) * 8192, bout + (size_t)l * 128,
            skip + l, ln_g + (size_t)l * 128, ln_b + (size_t)l * 128);
    }

    zero_kernel<<<(16512 / 4 + 255) / 256, 256, 0, stream>>>((float4*)psum, 16512 / 4);
    pool_graph<<<BB * 8, 256, 0, stream>>>(hB, x, batch, psum, pcnt);
    head_kernel<<<BB, 256, 0, stream>>>(psum, pcnt, task, Wtf, btf, Wc1, bc1, Wc2, bc2, out);
}

// Round 16
// 1142.150 us; speedup vs baseline: 1.0349x; 1.0349x over previous
//
#include <hip/hip_runtime.h>
#include <math.h>

// Problem constants (match reference)
#define NN 200000
#define EE 300000
#define BB 64
#define INV_SQRT_D 0.17677669529663687f

// ---- workspace layout in 4-byte words. Total ≈ 59.19M words = 236.7 MB.
// ws budget is ~256MB-class (252 passed, 329 faulted) -> stay <= 252 MB.
#define OFF_HB   ((size_t)0)                    // [N][64] uint (bf16x2) node features
#define OFF_P0   ((size_t)12800000)             // [N][64] uint: q, then vt_0, then vt_2
#define OFF_P1   ((size_t)25600000)             // [N][64] uint: kt_0 -> kt_1 -> vt_1
#define OFF_AS   ((size_t)38400000)             // [N][64] uint: kt_2 -> As accumulator
#define OFF_S    ((size_t)51200000)             // [3][E][4] f32 scores -> exp (CSR order)
#define OFF_RP   ((size_t)54800000)             // [3][N+1] int rowptr (padded 600016)
#define OFF_CP   ((size_t)55400016)             // [3][E] int2 (src,dst) per CSR position
#define OFF_WF   ((size_t)57200016)             // 14 x [128][128] f32 folded weights
#define OFF_BF   ((size_t)57429392)             // 14 x [128] f32 folded bias
#define OFF_BS   ((size_t)57431184)             // scan block sums 3*128 int
#define OFF_POOL ((size_t)57431568)             // psum [B][256] + pcnt [B][2] (16512)
#define OFF_WT   ((size_t)57448080)             // 16 x [128][64] uint packed W^T
#define OFF_IZ   ((size_t)57579152)             // [N][4] f32 softmax Z (atomic sum)
#define OFF_WIT  ((size_t)58379152)             // [128][52] uint packed Win^T
#define OFF_MX   ((size_t)58385808)             // [N][4] uint enc(max) (atomicMax)

#define SCAN_L   (NN + 1)
#define SCAN_E   8
#define SCAN_EPB (256 * SCAN_E)                          // 2048
#define SCAN_NB  ((SCAN_L + SCAN_EPB - 1) / SCAN_EPB)    // 98

typedef __attribute__((ext_vector_type(8))) short bf16x8;
typedef __attribute__((ext_vector_type(4))) float f32x4;

// Fast gelu: A&S 7.1.26 rational erf approx, |eps| <= 1.5e-7 absolute —
// 2+ orders below bf16 storage rounding of h. ~16 VALU ops vs ~50 for libm erff.
__device__ __forceinline__ float gelu_fast(float v) {
    float x = fabsf(v) * 0.70710678118654752f;
    float t = 1.0f / fmaf(0.3275911f, x, 1.0f);
    float p = fmaf(fmaf(fmaf(fmaf(1.061405429f, t, -1.453152027f), t, 1.421413741f),
                        t, -0.284496736f), t, 0.254829592f) * t;
    float er = 1.0f - p * __expf(-x * x);        // erf(|x|)
    er = copysignf(er, v);
    return 0.5f * v * (1.0f + er);
}
__device__ __forceinline__ float bflo(unsigned u) { return __uint_as_float(u << 16); }
__device__ __forceinline__ float bfhi(unsigned u) { return __uint_as_float(u & 0xffff0000u); }
__device__ __forceinline__ unsigned bfpack(float a, float b) {
    unsigned ua = __float_as_uint(a); ua += 0x7fffu + ((ua >> 16) & 1u);
    unsigned ub = __float_as_uint(b); ub += 0x7fffu + ((ub >> 16) & 1u);
    return (ua >> 16) | (ub & 0xffff0000u);
}
// Monotonic float<->uint encoding for atomicMax on floats.
// enc is strictly increasing in f; enc(any finite) > 0, so zero-init = -inf.
__device__ __forceinline__ unsigned fenc(float f) {
    unsigned u = __float_as_uint(f);
    return (u & 0x80000000u) ? ~u : (u | 0x80000000u);
}
__device__ __forceinline__ float fdec(unsigned e) {
    return __uint_as_float((e & 0x80000000u) ? (e & 0x7fffffffu) : ~e);
}

// ---- fold weights. 14 slots: per layer l: [l*7+0]=q copy, [l*7+1+r]=k@Wk_rel[r],
//      [l*7+4+r]=v@Wv_rel[r].  kqv split order is k|q|v (cols 0/128/256).
__global__ __launch_bounds__(256) void fold_weights(
    const float* __restrict__ Wkqv, const float* __restrict__ bkqv,
    const float* __restrict__ Wk_rel, const float* __restrict__ Wv_rel,
    float* __restrict__ Wf, float* __restrict__ bf)
{
    __shared__ float Wr[4096];
    const int b = blockIdx.x, t = threadIdx.x;
    const int l = b / 7, s = b % 7;
    const float* Wq = Wkqv + (size_t)l * 49152;   // [128][384]
    if (s == 0) {
        for (int i = t; i < 16384; i += 256) {
            int kk = i >> 7, c = i & 127;
            Wf[(size_t)b * 16384 + i] = Wq[kk * 384 + 128 + c];
        }
        if (t < 128) bf[b * 128 + t] = bkqv[l * 384 + 128 + t];
    } else {
        const int side = (s - 1) / 3, r = (s - 1) % 3;
        const int off = side ? 256 : 0;
        const float* Wrel = (side ? Wv_rel : Wk_rel) + (size_t)(l * 3 + r) * 4096;
        for (int i = t; i < 4096; i += 256) Wr[i] = Wrel[i];
        __syncthreads();
        for (int i = t; i < 16384; i += 256) {
            int kk = i >> 7, c = i & 127, hh = c >> 5, f = c & 31;
            const float* wrow = Wq + kk * 384 + off + hh * 32;
            const float* wr = Wr + hh * 1024 + f;
            float sum = 0.f;
#pragma unroll
            for (int d = 0; d < 32; ++d) sum += wrow[d] * wr[d * 32];
            Wf[(size_t)b * 16384 + i] = sum;
        }
        if (t < 128) {
            int hh = t >> 5, f = t & 31;
            float sum = 0.f;
#pragma unroll
            for (int d = 0; d < 32; ++d)
                sum += bkqv[l * 384 + off + hh * 32 + d] * Wr[hh * 1024 + d * 32 + f];
            bf[b * 128 + t] = sum;
        }
    }
}

// ---- pack W -> bf16x2-packed W^T: WT[slot][c][w] = (W[2w][c], W[2w+1][c]) ----
__global__ __launch_bounds__(256) void pack_wt(
    const float* __restrict__ W, unsigned* __restrict__ WT)
{
    const int slot = blockIdx.x, t = threadIdx.x;
    const float* Ws = W + (size_t)slot * 16384;
    unsigned* WTs = WT + (size_t)slot * 8192;
    for (int i = t; i < 8192; i += 256) {
        int c = i >> 6, w = i & 63;
        WTs[i] = bfpack(Ws[(size_t)(2 * w) * 128 + c], Ws[(size_t)(2 * w + 1) * 128 + c]);
    }
}

// ---- pack Win (69x128 f32) -> WinT bf16 [128][52] (K padded to 96 = 48 uints + 4 pad) ----
__global__ __launch_bounds__(256) void pack_win(
    const float* __restrict__ Win, unsigned* __restrict__ WinT)
{
    const int t = threadIdx.x;
    for (int i = t; i < 128 * 52; i += 256) {
        int c = i / 52, u = i - c * 52;
        unsigned v = 0;
        if (u < 34) {
            v = bfpack(Win[(size_t)(2 * u) * 128 + c], Win[(size_t)(2 * u + 1) * 128 + c]);
        } else if (u == 34) {
            v = bfpack(Win[(size_t)68 * 128 + c], 0.f);
        }
        WinT[i] = v;
    }
}

// ===================================================================
// MFMA C layout (16x16x32): col=lane&15, row=(lane>>4)*4+reg. Adjacent
// output cols live in xor-1 neighbor lanes: bias-add in-register,
// shfl_xor(1), pack bf16 pairs directly.
// Row-owning layout (R12): wave w = rows w*16..+15, all 128 cols, B in
// LDS (no write amplification). R13: 512-thread/128-row gemm blocks.
// R14: edge arrays fused to int2 pairs. R15: out_ln to 512-thread.
// R16: REVERTED R15's B1 register prefetch — PMC showed the compiler
// spilled pb[4] to scratch (FETCH +25MB, WRITE +50MB, dur 55->75us,
// VGPR pinned at 52). Back to R14's stage-after-barrier for B1.
// ===================================================================

// ---- MFMA input projection, 64-row blocks, single barrier ----
// K = 96 padded. B (WinT, 26.6KB) read directly from global (L1/L2-hot).
__global__ __launch_bounds__(256, 4) void input_proj_mfma(
    const float* __restrict__ x, const int* __restrict__ ast,
    const float* __restrict__ emb, const unsigned* __restrict__ WinT,
    const float* __restrict__ bin_, unsigned* __restrict__ h_bf)
{
    __shared__ unsigned Asm[64 * 52];    // 13312 B
    const int t = threadIdx.x;
    const int n0 = blockIdx.x * 64;
    const int w = t >> 6, lane = t & 63;
    const int m = lane & 15, quad = lane >> 4;
    // preload B fragments before staging (hides global latency under stage)
    bf16x8 b0[3], b1[3];
#pragma unroll
    for (int kc = 0; kc < 3; ++kc) {
        const int koff = kc * 16 + quad * 4;
        b0[kc] = *(const bf16x8*)(WinT + (size_t)(32 * w + m) * 52 + koff);
        b1[kc] = *(const bf16x8*)(WinT + (size_t)(32 * w + 16 + m) * 52 + koff);
    }
    // stage A (bf16): cols 0..63 = emb[ast[n]], 64..68 = x[n], 69..95 = 0
    for (int i = t; i < 64 * 32; i += 256) {           // emb part, branch-free
        int row = i >> 5, u = i & 31;
        float2 e = *(const float2*)(emb + (size_t)ast[n0 + row] * 64 + 2 * u);
        Asm[row * 52 + u] = bfpack(e.x, e.y);
    }
    if (t < 192) {                                     // x part: 3 uints per row
        int row = t / 3, j = t - (t / 3) * 3;
        const float* xr = x + (size_t)(n0 + row) * 5;
        float a = (j == 0) ? xr[0] : (j == 1) ? xr[2] : xr[4];
        float b = (j == 0) ? xr[1] : (j == 1) ? xr[3] : 0.f;
        Asm[row * 52 + 32 + j] = bfpack(a, b);
    }
    for (int i = t; i < 64 * 16; i += 256)             // zero pad u=35..50 (reads stop at 47)
        Asm[(i >> 4) * 52 + 35 + (i & 15)] = 0u;
    __syncthreads();
    f32x4 acc[4][2];
#pragma unroll
    for (int rt = 0; rt < 4; ++rt) { acc[rt][0] = (f32x4){0.f,0.f,0.f,0.f}; acc[rt][1] = acc[rt][0]; }
#pragma unroll
    for (int kc = 0; kc < 3; ++kc) {
        const int koff = kc * 16 + quad * 4;
#pragma unroll
        for (int rt = 0; rt < 4; ++rt) {
            bf16x8 a = *(const bf16x8*)&Asm[(rt * 16 + m) * 52 + koff];
            acc[rt][0] = __builtin_amdgcn_mfma_f32_16x16x32_bf16(a, b0[kc], acc[rt][0], 0, 0, 0);
            acc[rt][1] = __builtin_amdgcn_mfma_f32_16x16x32_bf16(a, b1[kc], acc[rt][1], 0, 0, 0);
        }
    }
    const float bv0 = bin_[32 * w + m], bv1 = bin_[32 * w + 16 + m];
    const int ub = 16 * w + 8 * (m & 1) + (m >> 1);
#pragma unroll
    for (int rt = 0; rt < 4; ++rt)
#pragma unroll
        for (int r = 0; r < 4; ++r) {
            float v0 = acc[rt][0][r] + bv0;
            float v1 = acc[rt][1][r] + bv1;
            float nv0 = __shfl_xor(v0, 1);
            float nv1 = __shfl_xor(v1, 1);
            unsigned pk = (m & 1) ? bfpack(nv1, v1) : bfpack(v0, nv0);
            h_bf[(size_t)(n0 + rt * 16 + quad * 4 + r) * 64 + ub] = pk;
        }
}

// ---- CSR build: histogram -> scan -> scatter ----
__global__ __launch_bounds__(256) void csr_hist(
    const int* __restrict__ ei0, const int* __restrict__ ei1, const int* __restrict__ ei2,
    int* __restrict__ rp)
{
    int idx = blockIdx.x * 256 + threadIdx.x;
    if (idx >= 3 * EE) return;
    int r = idx / EE, e = idx - r * EE;
    const int* ei = (r == 0) ? ei0 : ((r == 1) ? ei1 : ei2);
    atomicAdd(&rp[r * SCAN_L + ei[EE + e] + 1], 1);
}

__global__ __launch_bounds__(256) void scan1(int* __restrict__ rp, int* __restrict__ bs)
{
    __shared__ int ts[256];
    const int r = blockIdx.y;
    int* a = rp + (size_t)r * SCAN_L;
    const int base = blockIdx.x * SCAN_EPB + threadIdx.x * SCAN_E;
    int v[SCAN_E];
    int tot = 0;
#pragma unroll
    for (int j = 0; j < SCAN_E; ++j) {
        int idx = base + j;
        v[j] = (idx < SCAN_L) ? a[idx] : 0;
        tot += v[j];
    }
    ts[threadIdx.x] = tot;
    __syncthreads();
    for (int st = 1; st < 256; st <<= 1) {
        int add = (threadIdx.x >= st) ? ts[threadIdx.x - st] : 0;
        __syncthreads();
        ts[threadIdx.x] += add;
        __syncthreads();
    }
    int run = ts[threadIdx.x] - tot;
#pragma unroll
    for (int j = 0; j < SCAN_E; ++j) {
        run += v[j];
        int idx = base + j;
        if (idx < SCAN_L) a[idx] = run;
    }
    if (threadIdx.x == 255) bs[r * 128 + blockIdx.x] = ts[255];
}

__global__ __launch_bounds__(128) void scan2(int* __restrict__ bs)
{
    __shared__ int ts[128];
    const int r = blockIdx.x, t = threadIdx.x;
    int v = (t < SCAN_NB) ? bs[r * 128 + t] : 0;
    ts[t] = v;
    __syncthreads();
    for (int st = 1; st < 128; st <<= 1) {
        int add = (t >= st) ? ts[t - st] : 0;
        __syncthreads();
        ts[t] += add;
        __syncthreads();
    }
    bs[r * 128 + t] = ts[t];
}

__global__ __launch_bounds__(256) void scan3(int* __restrict__ rp, const int* __restrict__ bs)
{
    const int r = blockIdx.y;
    if (blockIdx.x == 0) return;
    const int off = bs[r * 128 + blockIdx.x - 1];
    const int base = blockIdx.x * SCAN_EPB + threadIdx.x * SCAN_E;
    int* a = rp + (size_t)r * SCAN_L;
#pragma unroll
    for (int j = 0; j < SCAN_E; ++j) {
        int idx = base + j;
        if (idx < SCAN_L) a[idx] += off;
    }
}

// ---- scatter: ONE int2 (src,dst) 8B store per edge (R14) ----
__global__ __launch_bounds__(256) void csr_scatter(
    const int* __restrict__ ei0, const int* __restrict__ ei1, const int* __restrict__ ei2,
    const int* __restrict__ rp, int* __restrict__ fill, int2* __restrict__ cpair)
{
    int idx = blockIdx.x * 256 + threadIdx.x;
    if (idx >= 3 * EE) return;
    int r = idx / EE, e = idx - r * EE;
    const int* ei = (r == 0) ? ei0 : ((r == 1) ? ei1 : ei2);
    int src = ei[e], dst = ei[EE + e];
    int pos = rp[r * SCAN_L + dst] + atomicAdd(&fill[r * NN + dst], 1);
    cpair[r * EE + pos] = make_int2(src, dst);
}

// ---- row-owning GEMM core: wave w = rows w*16..w*16+15, all 128 cols. ----
__device__ __forceinline__ void gemm_row_slot(
    const unsigned* Bsm, const bf16x8 a[4],
    int n0, int w, int m, int quad,
    const float* __restrict__ bias, unsigned* __restrict__ outp)
{
    float bo[8];
#pragma unroll
    for (int ct = 0; ct < 8; ++ct) bo[ct] = bias[ct * 16 + m];
    f32x4 acc[8];
#pragma unroll
    for (int ct = 0; ct < 8; ++ct) {
        acc[ct] = (f32x4){0.f, 0.f, 0.f, 0.f};
#pragma unroll
        for (int kc = 0; kc < 4; ++kc) {
            bf16x8 b = *(const bf16x8*)&Bsm[(ct * 16 + m) * 68 + kc * 16 + quad * 4];
            acc[ct] = __builtin_amdgcn_mfma_f32_16x16x32_bf16(a[kc], b, acc[ct], 0, 0, 0);
        }
    }
#pragma unroll
    for (int r = 0; r < 4; ++r) {
        const size_t n = (size_t)(n0 + w * 16 + quad * 4 + r);
        if (n < NN) {
#pragma unroll
            for (int cp = 0; cp < 4; ++cp) {
                float v0 = acc[2 * cp][r]     + bo[2 * cp];
                float v1 = acc[2 * cp + 1][r] + bo[2 * cp + 1];
                float nv0 = __shfl_xor(v0, 1);
                float nv1 = __shfl_xor(v1, 1);
                unsigned pk = (m & 1) ? bfpack(nv1, v1) : bfpack(v0, nv0);
                outp[n * 64 + cp * 16 + 8 * (m & 1) + (m >> 1)] = pk;
            }
        } else {
            // keep shuffles wave-uniform for inactive rows
#pragma unroll
            for (int cp = 0; cp < 4; ++cp) {
                float v0 = acc[2 * cp][r], v1 = acc[2 * cp + 1][r];
                (void)__shfl_xor(v0, 1); (void)__shfl_xor(v1, 1);
            }
        }
    }
}

// ---- 1-slot 128-row GEMM, row-owning, 512 threads (R13) ----
__global__ __launch_bounds__(512, 4) void gemm_mfma(
    const unsigned* __restrict__ in_bf, const unsigned* __restrict__ WT,
    const float* __restrict__ bias, unsigned* __restrict__ outp)
{
    __shared__ unsigned Asm[128 * 68];   // 34816 B
    __shared__ unsigned Bsm[128 * 68];   // 34816 B
    const int t = threadIdx.x;
    const int n0 = blockIdx.x * 128;
    const int w = t >> 6, lane = t & 63;
    const int m = lane & 15, quad = lane >> 4;
    for (int i = t; i < 128 * 16; i += 512) {
        int row = i >> 4, q4 = i & 15;
        size_t n = (size_t)(n0 + row); if (n >= NN) n = NN - 1;
        uint4 v = *(const uint4*)(in_bf + n * 64 + q4 * 4);
        *(uint4*)&Asm[row * 68 + q4 * 4] = v;
    }
    for (int i = t; i < 128 * 16; i += 512) {
        int row = i >> 4, q4 = i & 15;
        uint4 v = *(const uint4*)(WT + (size_t)row * 64 + q4 * 4);
        *(uint4*)&Bsm[row * 68 + q4 * 4] = v;
    }
    __syncthreads();
    bf16x8 a[4];
#pragma unroll
    for (int kc = 0; kc < 4; ++kc)
        a[kc] = *(const bf16x8*)&Asm[(w * 16 + m) * 68 + kc * 16 + quad * 4];
    gemm_row_slot(Bsm, a, n0, w, m, quad, bias, outp);
}

// ---- 2-slot 128-row GEMM, 512 threads: A staged/loaded once (R14 form) ----
__global__ __launch_bounds__(512, 4) void gemm_mfma2(
    const unsigned* __restrict__ in_bf,
    const unsigned* __restrict__ WT0, const float* __restrict__ bias0,
    unsigned* __restrict__ out0,
    const unsigned* __restrict__ WT1, const float* __restrict__ bias1,
    unsigned* __restrict__ out1)
{
    __shared__ unsigned Asm[128 * 68];
    __shared__ unsigned Bsm[128 * 68];
    const int t = threadIdx.x;
    const int n0 = blockIdx.x * 128;
    const int w = t >> 6, lane = t & 63;
    const int m = lane & 15, quad = lane >> 4;
    for (int i = t; i < 128 * 16; i += 512) {
        int row = i >> 4, q4 = i & 15;
        size_t n = (size_t)(n0 + row); if (n >= NN) n = NN - 1;
        uint4 v = *(const uint4*)(in_bf + n * 64 + q4 * 4);
        *(uint4*)&Asm[row * 68 + q4 * 4] = v;
    }
    for (int i = t; i < 128 * 16; i += 512) {
        int row = i >> 4, q4 = i & 15;
        uint4 v = *(const uint4*)(WT0 + (size_t)row * 64 + q4 * 4);
        *(uint4*)&Bsm[row * 68 + q4 * 4] = v;
    }
    __syncthreads();
    bf16x8 a[4];
#pragma unroll
    for (int kc = 0; kc < 4; ++kc)
        a[kc] = *(const bf16x8*)&Asm[(w * 16 + m) * 68 + kc * 16 + quad * 4];
    gemm_row_slot(Bsm, a, n0, w, m, quad, bias0, out0);
    __syncthreads();                       // all waves done reading B0
    for (int i = t; i < 128 * 16; i += 512) {
        int row = i >> 4, q4 = i & 15;
        uint4 v = *(const uint4*)(WT1 + (size_t)row * 64 + q4 * 4);
        *(uint4*)&Bsm[row * 68 + q4 * 4] = v;
    }
    __syncthreads();
    gemm_row_slot(Bsm, a, n0, w, m, quad, bias1, out1);
}

// ---- edge scores in CSR position order; also atomicMax the per-(dst,head)
//      running max. (src,dst) from one int2 load (R14). ----
__global__ __launch_bounds__(256) void edge_scores_csr(
    const unsigned* __restrict__ q_bf, const unsigned* __restrict__ k_bf,
    const int2* __restrict__ cpair,
    const float* __restrict__ p4, float* __restrict__ s_out,
    unsigned* __restrict__ mxi)
{
    int idx = blockIdx.x * 256 + threadIdx.x;
    if (idx >= EE * 4) return;
    int p = idx >> 2, hh = idx & 3;
    int2 pr = cpair[p];
    int src = pr.x, dst = pr.y;
    const uint4* qp = (const uint4*)(q_bf + (size_t)dst * 64 + hh * 16);
    const uint4* kp = (const uint4*)(k_bf + (size_t)src * 64 + hh * 16);
    float sum = 0.f;
#pragma unroll
    for (int i = 0; i < 4; ++i) {
        uint4 qa = qp[i], ka = kp[i];
        sum += bflo(qa.x) * bflo(ka.x) + bfhi(qa.x) * bfhi(ka.x);
        sum += bflo(qa.y) * bflo(ka.y) + bfhi(qa.y) * bfhi(ka.y);
        sum += bflo(qa.z) * bflo(ka.z) + bfhi(qa.z) * bfhi(ka.z);
        sum += bflo(qa.w) * bflo(ka.w) + bfhi(qa.w) * bfhi(ka.w);
    }
    float s = sum * p4[hh] * INV_SQRT_D;
    s_out[(size_t)p * 4 + hh] = s;
    atomicMax(&mxi[(size_t)dst * 4 + hh], fenc(s));
}

// ---- edge_exp_z: one edge-parallel pass after all 3 relations' scores:
//      e = exp(s - m[dst]); overwrite s with e; atomicAdd Z[dst]. ----
__global__ __launch_bounds__(256) void edge_exp_z(
    float* __restrict__ s, const int2* __restrict__ cpair,
    const unsigned* __restrict__ mxi, float* __restrict__ Z)
{
    int idx = blockIdx.x * 256 + threadIdx.x;
    if (idx >= 3 * EE * 4) return;
    int p = idx >> 2, hh = idx & 3;
    int dst = cpair[p].y;
    float m = fdec(mxi[(size_t)dst * 4 + hh]);
    float e = __expf(s[idx] - m);
    s[idx] = e;
    atomicAdd(&Z[(size_t)dst * 4 + hh], e);
}

// ---- agg_reg: 16-lane-group-per-dst register aggregation (4 dsts/wave).
//      Lane sl=lane&15 owns uint4 = cols 8*sl..8*sl+7 (one head: hh=sl>>2).
//      src from cpair[].x (wave-uniform per group -> broadcast load). ----
template<int NREL, int FIRST>
__global__ __launch_bounds__(256, 8) void agg_reg(
    const unsigned* __restrict__ pA, const unsigned* __restrict__ pB,
    const float* __restrict__ s, const int* __restrict__ rp,
    const int2* __restrict__ cpair, int ra, int rb,
    const float* __restrict__ Z, unsigned* __restrict__ As_g)
{
    const int lane = threadIdx.x & 63;
    const int sl = lane & 15;                 // sub-lane within dst group
    const int dst = blockIdx.x * 16 + (threadIdx.x >> 6) * 4 + (lane >> 4);
    const int hh = sl >> 2;                   // head of this lane's 8 cols
    float zz = Z[(size_t)dst * 4 + hh];
    float iz = 1.f / (zz + 1e-16f);
    float a0 = 0.f, a1 = 0.f, a2 = 0.f, a3 = 0.f;
    float a4 = 0.f, a5 = 0.f, a6 = 0.f, a7 = 0.f;
#pragma unroll
    for (int q = 0; q < NREL; ++q) {
        const unsigned* pl = q ? pB : pA;
        const int r = q ? rb : ra;
        const int beg = rp[r * SCAN_L + dst];
        const int end = rp[r * SCAN_L + dst + 1];
        int p = beg;
        for (; p + 1 < end; p += 2) {
            int s0 = cpair[r * EE + p].x;
            float al0 = s[((size_t)r * EE + p) * 4 + hh];
            int s1 = cpair[r * EE + p + 1].x;
            float al1 = s[((size_t)r * EE + p + 1) * 4 + hh];
            uint4 v0 = *(const uint4*)(pl + (size_t)s0 * 64 + sl * 4);
            uint4 v1 = *(const uint4*)(pl + (size_t)s1 * 64 + sl * 4);
            a0 += al0 * bflo(v0.x) + al1 * bflo(v1.x);
            a1 += al0 * bfhi(v0.x) + al1 * bfhi(v1.x);
            a2 += al0 * bflo(v0.y) + al1 * bflo(v1.y);
            a3 += al0 * bfhi(v0.y) + al1 * bfhi(v1.y);
            a4 += al0 * bflo(v0.z) + al1 * bflo(v1.z);
            a5 += al0 * bfhi(v0.z) + al1 * bfhi(v1.z);
            a6 += al0 * bflo(v0.w) + al1 * bflo(v1.w);
            a7 += al0 * bfhi(v0.w) + al1 * bfhi(v1.w);
        }
        if (p < end) {
            int s0 = cpair[r * EE + p].x;
            float al0 = s[((size_t)r * EE + p) * 4 + hh];
            uint4 v0 = *(const uint4*)(pl + (size_t)s0 * 64 + sl * 4);
            a0 += al0 * bflo(v0.x); a1 += al0 * bfhi(v0.x);
            a2 += al0 * bflo(v0.y); a3 += al0 * bfhi(v0.y);
            a4 += al0 * bflo(v0.z); a5 += al0 * bfhi(v0.z);
            a6 += al0 * bflo(v0.w); a7 += al0 * bfhi(v0.w);
        }
    }
    a0 *= iz; a1 *= iz; a2 *= iz; a3 *= iz;
    a4 *= iz; a5 *= iz; a6 *= iz; a7 *= iz;
    unsigned* op = As_g + (size_t)dst * 64 + sl * 4;
    if (FIRST) {
        uint4 o;
        o.x = bfpack(a0, a1); o.y = bfpack(a2, a3);
        o.z = bfpack(a4, a5); o.w = bfpack(a6, a7);
        *(uint4*)op = o;
    } else {
        uint4 old = *(const uint4*)op;
        uint4 o;
        o.x = bfpack(gelu_fast(bflo(old.x) + a0), gelu_fast(bfhi(old.x) + a1));
        o.y = bfpack(gelu_fast(bflo(old.y) + a2), gelu_fast(bfhi(old.y) + a3));
        o.z = bfpack(gelu_fast(bflo(old.z) + a4), gelu_fast(bfhi(old.z) + a5));
        o.w = bfpack(gelu_fast(bflo(old.w) + a6), gelu_fast(bfhi(old.w) + a7));
        *(uint4*)op = o;
    }
}

// ---- out_ln: As(pre-gelu'd) @ Wout + bout -> skip -> LN -> h ----
// R9: wave owns 16 complete rows x 128 cols; one 16-lane butterfly per row.
// R11: B panel in LDS. R15: 512-thread/128-row blocks (kept — saved ~70us).
__global__ __launch_bounds__(512, 4) void out_ln(
    const unsigned* __restrict__ As_g, unsigned* __restrict__ h_bf,
    const unsigned* __restrict__ WT, const float* __restrict__ bout,
    const float* __restrict__ skipp, const float* __restrict__ lg,
    const float* __restrict__ lb)
{
    __shared__ unsigned Asm[128 * 68];   // 34816 B
    __shared__ unsigned Bsm[128 * 68];   // 34816 B
    const int t = threadIdx.x;
    const int n0 = blockIdx.x * 128;
    const int w = t >> 6, lane = t & 63;
    const int m = lane & 15, quad = lane >> 4;
    // stage A (pre-gelu'd As) and B (WT slot) to LDS, coalesced
    for (int i = t; i < 128 * 16; i += 512) {
        int row = i >> 4, q4 = i & 15;
        size_t n = (size_t)(n0 + row); if (n >= NN) n = NN - 1;
        uint4 v = *(const uint4*)(As_g + n * 64 + q4 * 4);
        *(uint4*)&Asm[row * 68 + q4 * 4] = v;
    }
    for (int i = t; i < 128 * 16; i += 512) {
        int row = i >> 4, q4 = i & 15;
        uint4 v = *(const uint4*)(WT + (size_t)row * 64 + q4 * 4);
        *(uint4*)&Bsm[row * 68 + q4 * 4] = v;
    }
    // per-col constants for this lane's 8 col-tiles (col = ct*16+m)
    float bo[8], g8[8], lb8[8];
#pragma unroll
    for (int ct = 0; ct < 8; ++ct) {
        bo[ct]  = bout[ct * 16 + m];
        g8[ct]  = lg[ct * 16 + m];
        lb8[ct] = lb[ct * 16 + m];
    }
    const float alpha = 1.f / (1.f + expf(-skipp[0]));
    const float om = 1.f - alpha;
    __syncthreads();
    // lane's A row = w*16+m (4 b128 LDS reads)
    bf16x8 a[4];
#pragma unroll
    for (int kc = 0; kc < 4; ++kc)
        a[kc] = *(const bf16x8*)&Asm[(w * 16 + m) * 68 + kc * 16 + quad * 4];
    // MFMA over 8 col-tiles; B from LDS
    f32x4 acc[8];
#pragma unroll
    for (int ct = 0; ct < 8; ++ct) {
        acc[ct] = (f32x4){0.f, 0.f, 0.f, 0.f};
#pragma unroll
        for (int kc = 0; kc < 4; ++kc) {
            bf16x8 b = *(const bf16x8*)&Bsm[(ct * 16 + m) * 68 + kc * 16 + quad * 4];
            acc[ct] = __builtin_amdgcn_mfma_f32_16x16x32_bf16(a[kc], b, acc[ct], 0, 0, 0);
        }
    }
    // o = alpha*(C+bout) + (1-alpha)*h_old; lane's output rows: w*16+quad*4+r
    const bool hi = (m & 1);
#pragma unroll
    for (int ct = 0; ct < 8; ++ct)
#pragma unroll
        for (int r = 0; r < 4; ++r) {
            size_t n = (size_t)(n0 + w * 16 + quad * 4 + r);
            if (n >= NN) n = NN - 1;            // clamped read (unused rows)
            unsigned hu = h_bf[n * 64 + ct * 8 + (m >> 1)];
            float p = hi ? bfhi(hu) : bflo(hu);
            acc[ct][r] = alpha * (acc[ct][r] + bo[ct]) + om * p;
        }
    // LN + pack + store, fully within the 16-lane group (n uniform per group)
#pragma unroll
    for (int r = 0; r < 4; ++r) {
        float po = 0.f, pq = 0.f;
#pragma unroll
        for (int ct = 0; ct < 8; ++ct) {
            float o = acc[ct][r];
            po += o;
            pq += o * o;
        }
#pragma unroll
        for (int sshf = 1; sshf < 16; sshf <<= 1) {
            po += __shfl_xor(po, sshf);
            pq += __shfl_xor(pq, sshf);
        }
        float mu = po * (1.f / 128.f);
        float var = pq * (1.f / 128.f) - mu * mu;
        float rs = rsqrtf(var + 1e-5f);
        const size_t n = (size_t)(n0 + w * 16 + quad * 4 + r);
        if (n < NN) {
#pragma unroll
            for (int cp = 0; cp < 4; ++cp) {
                float v0 = (acc[2 * cp][r]     - mu) * rs * g8[2 * cp]     + lb8[2 * cp];
                float v1 = (acc[2 * cp + 1][r] - mu) * rs * g8[2 * cp + 1] + lb8[2 * cp + 1];
                float nv0 = __shfl_xor(v0, 1);
                float nv1 = __shfl_xor(v1, 1);
                unsigned pk = (m & 1) ? bfpack(nv1, v1) : bfpack(v0, nv0);
                h_bf[n * 64 + cp * 16 + 8 * (m & 1) + (m >> 1)] = pk;
            }
        } else {
#pragma unroll
            for (int cp = 0; cp < 4; ++cp) {
                float v0 = acc[2 * cp][r], v1 = acc[2 * cp + 1][r];
                (void)__shfl_xor(v0, 1); (void)__shfl_xor(v1, 1);
            }
        }
    }
}

// ---- pool_graph: 8 chunks/graph; single-graph blocks -> register accumulate,
//      LDS reduce, 260 global atomics per block ----
__global__ __launch_bounds__(256) void pool_graph(
    const unsigned* __restrict__ h_bf, const float* __restrict__ x,
    const int* __restrict__ batch, float* __restrict__ psum, float* __restrict__ pcnt)
{
    __shared__ float ls[258];
    const int b = blockIdx.x >> 3;
    const int chunk = blockIdx.x & 7;
    const int t = threadIdx.x;
    int lo = 0, hi = NN;
    while (lo < hi) { int mid = (lo + hi) >> 1; if (batch[mid] < b) lo = mid + 1; else hi = mid; }
    const int start = lo;
    lo = 0; hi = NN;
    while (lo < hi) { int mid = (lo + hi) >> 1; if (batch[mid] < b + 1) lo = mid + 1; else hi = mid; }
    const int end = lo;
    const int len = end - start;
    const int c0 = start + (int)(((long long)len * chunk) >> 3);
    const int c1 = start + (int)(((long long)len * (chunk + 1)) >> 3);
    for (int i = t; i < 258; i += 256) ls[i] = 0.f;
    __syncthreads();
    const int c2 = t & 63;
    const int rs = t >> 6;
    float sw0 = 0.f, sw1 = 0.f, sn0 = 0.f, sn1 = 0.f, cw = 0.f, cn = 0.f;
    for (int n = c0 + rs; n < c1; n += 4) {
        float w = (x[(size_t)n * 5 + 1] > 0.f) ? 1.f : 0.f;
        unsigned u = h_bf[(size_t)n * 64 + c2];
        float h0 = bflo(u), h1 = bfhi(u);
        sw0 += w * h0; sw1 += w * h1;
        sn0 += (1.f - w) * h0; sn1 += (1.f - w) * h1;
        cw += w; cn += 1.f - w;
    }
    atomicAdd(&ls[c2 * 4 + 0], sw0);
    atomicAdd(&ls[c2 * 4 + 1], sw1);
    atomicAdd(&ls[c2 * 4 + 2], sn0);
    atomicAdd(&ls[c2 * 4 + 3], sn1);
    if (c2 == 0) { atomicAdd(&ls[256], cw); atomicAdd(&ls[257], cn); }
    __syncthreads();
    if (t < 64) {
        atomicAdd(&psum[b * 256 + 2 * t],       ls[t * 4 + 0]);
        atomicAdd(&psum[b * 256 + 2 * t + 1],   ls[t * 4 + 1]);
        atomicAdd(&psum[b * 256 + 128 + 2 * t],     ls[t * 4 + 2]);
        atomicAdd(&psum[b * 256 + 128 + 2 * t + 1], ls[t * 4 + 3]);
    } else if (t == 64) {
        atomicAdd(&pcnt[b * 2], ls[256]);
        atomicAdd(&pcnt[b * 2 + 1], ls[257]);
    }
}

// ---------------- MLP head (pool finalize fused) ----------------
__global__ __launch_bounds__(256) void head_kernel(
    const float* __restrict__ psum, const float* __restrict__ pcnt,
    const float* __restrict__ task,
    const float* __restrict__ Wtf, const float* __restrict__ btf,
    const float* __restrict__ Wc1, const float* __restrict__ bc1,
    const float* __restrict__ Wc2, const float* __restrict__ bc2,
    float* __restrict__ out)
{
    __shared__ float in_s[640];
    __shared__ float ge_s[256];
    __shared__ float hc_s[64];
    const int b = blockIdx.x, t = threadIdx.x;
    if (t < 256) {
        float cnt = pcnt[b * 2 + (t >> 7)];
        float sv = psum[b * 256 + t];
        in_s[t] = (cnt > 0.f) ? sv / fmaxf(cnt, 1.f) : 0.f;
    }
    for (int i = t; i < 384; i += 256) in_s[256 + i] = task[b * 384 + i];
    __syncthreads();
    float acc = btf[t];
    for (int i = 0; i < 640; ++i) acc += in_s[i] * Wtf[i * 256 + t];
    ge_s[t] = fmaxf(acc, 0.f);
    __syncthreads();
    if (t < 64) {
        float a2 = bc1[t];
        for (int i = 0; i < 256; ++i) a2 += ge_s[i] * Wc1[i * 64 + t];
        hc_s[t] = fmaxf(a2, 0.f);
    }
    __syncthreads();
    if (t < 64) {
        float v = hc_s[t] * Wc2[t];
#pragma unroll
        for (int off = 32; off >= 1; off >>= 1) v += __shfl_down(v, off);
        if (t == 0) out[b] = v + bc2[0];
    }
}

__global__ __launch_bounds__(256) void zero_kernel(float4* __restrict__ p, int count4)
{
    int i = blockIdx.x * 256 + threadIdx.x;
    if (i < count4) p[i] = make_float4(0.f, 0.f, 0.f, 0.f);
}

extern "C" void kernel_launch(void* const* d_in, const int* in_sizes, int n_in,
                              void* d_out, int out_size, void* d_ws, size_t ws_size,
                              hipStream_t stream)
{
    const float* x      = (const float*)d_in[0];
    const int*   ast    = (const int*)d_in[1];
    const int*   batch  = (const int*)d_in[2];
    const int*   ei[3]  = {(const int*)d_in[3], (const int*)d_in[4], (const int*)d_in[5]};
    const float* task   = (const float*)d_in[6];
    const float* emb    = (const float*)d_in[7];
    const float* Win    = (const float*)d_in[8];
    const float* bin_   = (const float*)d_in[9];
    const float* Wkqv   = (const float*)d_in[10];
    const float* bkqv   = (const float*)d_in[11];
    const float* Wk_rel = (const float*)d_in[12];
    const float* Wv_rel = (const float*)d_in[13];
    const float* p_rel  = (const float*)d_in[14];
    const float* Wout   = (const float*)d_in[15];
    const float* bout   = (const float*)d_in[16];
    const float* skip   = (const float*)d_in[17];
    const float* ln_g   = (const float*)d_in[18];
    const float* ln_b   = (const float*)d_in[19];
    const float* Wtf    = (const float*)d_in[20];
    const float* btf    = (const float*)d_in[21];
    const float* Wc1    = (const float*)d_in[22];
    const float* bc1    = (const float*)d_in[23];
    const float* Wc2    = (const float*)d_in[24];
    const float* bc2    = (const float*)d_in[25];
    float* out = (float*)d_out;
    float* ws  = (float*)d_ws;

    unsigned* hB   = (unsigned*)(ws + OFF_HB);
    unsigned* P0   = (unsigned*)(ws + OFF_P0);   // q -> vt_0 -> vt_2
    unsigned* P1   = (unsigned*)(ws + OFF_P1);   // kt_0 -> kt_1 -> vt_1
    unsigned* AS   = (unsigned*)(ws + OFF_AS);   // kt_2 -> As accumulator
    float*    sbuf = ws + OFF_S;
    int*      rp   = (int*)(ws + OFF_RP);
    int2*     cpair= (int2*)(ws + OFF_CP);
    int*      fill = (int*)(ws + OFF_P0);        // aliases P0 during CSR build only
    float*    Wf   = ws + OFF_WF;
    float*    bf   = ws + OFF_BF;
    int*      bs   = (int*)(ws + OFF_BS);
    float*    psum = ws + OFF_POOL;
    float*    pcnt = psum + (size_t)BB * 256;
    unsigned* WT   = (unsigned*)(ws + OFF_WT);   // 14 gemm slots + 2 Wout slots
    float*    Zbuf = ws + OFF_IZ;                // [N][4] softmax Z (atomic sum)
    unsigned* WinT = (unsigned*)(ws + OFF_WIT);
    unsigned* mxi  = (unsigned*)(ws + OFF_MX);   // [N][4] enc(max)

    fold_weights<<<14, 256, 0, stream>>>(Wkqv, bkqv, Wk_rel, Wv_rel, Wf, bf);
    pack_wt<<<14, 256, 0, stream>>>(Wf, WT);
    pack_wt<<<2, 256, 0, stream>>>(Wout, WT + (size_t)14 * 8192);
    pack_win<<<1, 256, 0, stream>>>(Win, WinT);
    input_proj_mfma<<<NN / 64, 256, 0, stream>>>(x, ast, emb, WinT, bin_, hB);

    zero_kernel<<<(600016 / 4 + 255) / 256, 256, 0, stream>>>((float4*)rp, 600016 / 4);
    zero_kernel<<<(600000 / 4 + 255) / 256, 256, 0, stream>>>((float4*)fill, 600000 / 4);
    csr_hist<<<(3 * EE + 255) / 256, 256, 0, stream>>>(ei[0], ei[1], ei[2], rp);
    scan1<<<dim3(SCAN_NB, 3), 256, 0, stream>>>(rp, bs);
    scan2<<<3, 128, 0, stream>>>(bs);
    scan3<<<dim3(SCAN_NB, 3), 256, 0, stream>>>(rp, bs);
    csr_scatter<<<(3 * EE + 255) / 256, 256, 0, stream>>>(
        ei[0], ei[1], ei[2], rp, fill, cpair);

    const int GG = (NN + 127) / 128;   // 1563 (tail-guarded)
    for (int l = 0; l < 2; ++l) {
        const size_t ls = (size_t)l * 7;   // slots: 0=q, 1..3=kt_r, 4..6=vt_r
        // zero-init softmax stats (enc(-inf) < 0+; Z = 0)
        zero_kernel<<<(800000 / 4 + 255) / 256, 256, 0, stream>>>((float4*)mxi, 800000 / 4);
        zero_kernel<<<(800000 / 4 + 255) / 256, 256, 0, stream>>>((float4*)Zbuf, 800000 / 4);
        // q -> P0, kt_0 -> P1
        gemm_mfma2<<<GG, 512, 0, stream>>>(
            hB, WT + ls * 8192, bf + ls * 128, P0,
            WT + (ls + 1) * 8192, bf + (ls + 1) * 128, P1);
        edge_scores_csr<<<(EE * 4 + 255) / 256, 256, 0, stream>>>(
            P0, P1, cpair, p_rel + (size_t)l * 12, sbuf, mxi);
        // kt_1 -> P1 (kt_0 consumed), kt_2 -> AS (dead until agg)
        gemm_mfma2<<<GG, 512, 0, stream>>>(
            hB, WT + (ls + 2) * 8192, bf + (ls + 2) * 128, P1,
            WT + (ls + 3) * 8192, bf + (ls + 3) * 128, AS);
        edge_scores_csr<<<(EE * 4 + 255) / 256, 256, 0, stream>>>(
            P0, P1, cpair + (size_t)EE,
            p_rel + (size_t)(l * 3 + 1) * 4, sbuf + (size_t)EE * 4, mxi);
        edge_scores_csr<<<(EE * 4 + 255) / 256, 256, 0, stream>>>(
            P0, AS, cpair + (size_t)2 * EE,
            p_rel + (size_t)(l * 3 + 2) * 4, sbuf + (size_t)2 * EE * 4, mxi);
        // edge-parallel exp + Z accumulation (all 3 relations at once)
        edge_exp_z<<<(3 * EE * 4 + 255) / 256, 256, 0, stream>>>(sbuf, cpair, mxi, Zbuf);
        // vt_0 -> P0 (q dead), vt_1 -> P1
        gemm_mfma2<<<GG, 512, 0, stream>>>(
            hB, WT + (ls + 4) * 8192, bf + (ls + 4) * 128, P0,
            WT + (ls + 5) * 8192, bf + (ls + 5) * 128, P1);
        agg_reg<2, 1><<<NN / 16, 256, 0, stream>>>(P0, P1, sbuf, rp, cpair, 0, 1, Zbuf, AS);
        gemm_mfma<<<GG, 512, 0, stream>>>(hB, WT + (ls + 6) * 8192, bf + (ls + 6) * 128, P0);
        agg_reg<1, 0><<<NN / 16, 256, 0, stream>>>(P0, P0, sbuf, rp, cpair, 2, 2, Zbuf, AS);
        out_ln<<<GG, 512, 0, stream>>>(
            AS, hB, WT + (size_t)(14 + l) * 8192, bout + (size_t)l * 128,
            skip + l, ln_g + (size_t)l * 128, ln_b + (size_t)l * 128);
    }

    zero_kernel<<<(16512 / 4 + 255) / 256, 256, 0, stream>>>((float4*)psum, 16512 / 4);
    pool_graph<<<BB * 8, 256, 0, stream>>>(hB, x, batch, psum, pcnt);
    head_kernel<<<BB, 256, 0, stream>>>(psum, pcnt, task, Wtf, btf, Wc1, bc1, Wc2, bc2, out);
}

// Round 18
// 1069.768 us; speedup vs baseline: 1.1049x; 1.0677x over previous
//
#include <hip/hip_runtime.h>
#include <math.h>

// Problem constants (match reference)
#define NN 200000
#define EE 300000
#define BB 64
#define INV_SQRT_D 0.17677669529663687f

// ---- workspace layout in 4-byte words. Total ≈ 59.19M words = 236.7 MB.
// ws budget is ~256MB-class (252 passed, 329 faulted) -> stay <= 252 MB.
#define OFF_HB   ((size_t)0)                    // [N][64] uint (bf16x2) node features
#define OFF_P0   ((size_t)12800000)             // [N][64] uint: q, then vt_0, then vt_2
#define OFF_P1   ((size_t)25600000)             // [N][64] uint: kt_0 -> kt_1 -> vt_1
#define OFF_AS   ((size_t)38400000)             // [N][64] uint: kt_2 -> As accumulator
#define OFF_S    ((size_t)51200000)             // [3][E][4] f32 RAW scores (CSR order)
#define OFF_RP   ((size_t)54800000)             // [3][N+1] int rowptr (padded 600016)
#define OFF_CP   ((size_t)55400016)             // [3][E] int2 (src,dst) per CSR position
#define OFF_WF   ((size_t)57200016)             // 14 x [128][128] f32 folded weights
#define OFF_BF   ((size_t)57429392)             // 14 x [128] f32 folded bias
#define OFF_BS   ((size_t)57431184)             // scan block sums 3*128 int
#define OFF_POOL ((size_t)57431568)             // psum [B][256] + pcnt [B][2] (16512)
#define OFF_WT   ((size_t)57448080)             // 16 x [128][64] uint packed W^T
#define OFF_IZ   ((size_t)57579152)             // [N][4] f32 softmax z01 partial (plain store)
#define OFF_WIT  ((size_t)58379152)             // [128][52] uint packed Win^T
#define OFF_MX   ((size_t)58385808)             // [N][4] uint enc(max) (atomicMax)

#define SCAN_L   (NN + 1)
#define SCAN_E   8
#define SCAN_EPB (256 * SCAN_E)                          // 2048
#define SCAN_NB  ((SCAN_L + SCAN_EPB - 1) / SCAN_EPB)    // 98

typedef __attribute__((ext_vector_type(8))) short bf16x8;
typedef __attribute__((ext_vector_type(4))) float f32x4;

// Fast gelu: A&S 7.1.26 rational erf approx, |eps| <= 1.5e-7 absolute —
// 2+ orders below bf16 storage rounding of h. ~16 VALU ops vs ~50 for libm erff.
__device__ __forceinline__ float gelu_fast(float v) {
    float x = fabsf(v) * 0.70710678118654752f;
    float t = 1.0f / fmaf(0.3275911f, x, 1.0f);
    float p = fmaf(fmaf(fmaf(fmaf(1.061405429f, t, -1.453152027f), t, 1.421413741f),
                        t, -0.284496736f), t, 0.254829592f) * t;
    float er = 1.0f - p * __expf(-x * x);        // erf(|x|)
    er = copysignf(er, v);
    return 0.5f * v * (1.0f + er);
}
__device__ __forceinline__ float bflo(unsigned u) { return __uint_as_float(u << 16); }
__device__ __forceinline__ float bfhi(unsigned u) { return __uint_as_float(u & 0xffff0000u); }
__device__ __forceinline__ unsigned bfpack(float a, float b) {
    unsigned ua = __float_as_uint(a); ua += 0x7fffu + ((ua >> 16) & 1u);
    unsigned ub = __float_as_uint(b); ub += 0x7fffu + ((ub >> 16) & 1u);
    return (ua >> 16) | (ub & 0xffff0000u);
}
// Monotonic float<->uint encoding for atomicMax on floats.
// enc is strictly increasing in f; enc(any finite) > 0, so zero-init = -inf.
__device__ __forceinline__ unsigned fenc(float f) {
    unsigned u = __float_as_uint(f);
    return (u & 0x80000000u) ? ~u : (u | 0x80000000u);
}
__device__ __forceinline__ float fdec(unsigned e) {
    return __uint_as_float((e & 0x80000000u) ? (e & 0x7fffffffu) : ~e);
}

// ---- fold weights. 14 slots: per layer l: [l*7+0]=q copy, [l*7+1+r]=k@Wk_rel[r],
//      [l*7+4+r]=v@Wv_rel[r].  kqv split order is k|q|v (cols 0/128/256).
__global__ __launch_bounds__(256) void fold_weights(
    const float* __restrict__ Wkqv, const float* __restrict__ bkqv,
    const float* __restrict__ Wk_rel, const float* __restrict__ Wv_rel,
    float* __restrict__ Wf, float* __restrict__ bf)
{
    __shared__ float Wr[4096];
    const int b = blockIdx.x, t = threadIdx.x;
    const int l = b / 7, s = b % 7;
    const float* Wq = Wkqv + (size_t)l * 49152;   // [128][384]
    if (s == 0) {
        for (int i = t; i < 16384; i += 256) {
            int kk = i >> 7, c = i & 127;
            Wf[(size_t)b * 16384 + i] = Wq[kk * 384 + 128 + c];
        }
        if (t < 128) bf[b * 128 + t] = bkqv[l * 384 + 128 + t];
    } else {
        const int side = (s - 1) / 3, r = (s - 1) % 3;
        const int off = side ? 256 : 0;
        const float* Wrel = (side ? Wv_rel : Wk_rel) + (size_t)(l * 3 + r) * 4096;
        for (int i = t; i < 4096; i += 256) Wr[i] = Wrel[i];
        __syncthreads();
        for (int i = t; i < 16384; i += 256) {
            int kk = i >> 7, c = i & 127, hh = c >> 5, f = c & 31;
            const float* wrow = Wq + kk * 384 + off + hh * 32;
            const float* wr = Wr + hh * 1024 + f;
            float sum = 0.f;
#pragma unroll
            for (int d = 0; d < 32; ++d) sum += wrow[d] * wr[d * 32];
            Wf[(size_t)b * 16384 + i] = sum;
        }
        if (t < 128) {
            int hh = t >> 5, f = t & 31;
            float sum = 0.f;
#pragma unroll
            for (int d = 0; d < 32; ++d)
                sum += bkqv[l * 384 + off + hh * 32 + d] * Wr[hh * 1024 + d * 32 + f];
            bf[b * 128 + t] = sum;
        }
    }
}

// ---- pack W -> bf16x2-packed W^T: WT[slot][c][w] = (W[2w][c], W[2w+1][c]) ----
__global__ __launch_bounds__(256) void pack_wt(
    const float* __restrict__ W, unsigned* __restrict__ WT)
{
    const int slot = blockIdx.x, t = threadIdx.x;
    const float* Ws = W + (size_t)slot * 16384;
    unsigned* WTs = WT + (size_t)slot * 8192;
    for (int i = t; i < 8192; i += 256) {
        int c = i >> 6, w = i & 63;
        WTs[i] = bfpack(Ws[(size_t)(2 * w) * 128 + c], Ws[(size_t)(2 * w + 1) * 128 + c]);
    }
}

// ---- pack Win (69x128 f32) -> WinT bf16 [128][52] (K padded to 96 = 48 uints + 4 pad) ----
__global__ __launch_bounds__(256) void pack_win(
    const float* __restrict__ Win, unsigned* __restrict__ WinT)
{
    const int t = threadIdx.x;
    for (int i = t; i < 128 * 52; i += 256) {
        int c = i / 52, u = i - c * 52;
        unsigned v = 0;
        if (u < 34) {
            v = bfpack(Win[(size_t)(2 * u) * 128 + c], Win[(size_t)(2 * u + 1) * 128 + c]);
        } else if (u == 34) {
            v = bfpack(Win[(size_t)68 * 128 + c], 0.f);
        }
        WinT[i] = v;
    }
}

// ===================================================================
// MFMA C layout (16x16x32): col=lane&15, row=(lane>>4)*4+reg. Adjacent
// output cols live in xor-1 neighbor lanes: bias-add in-register,
// shfl_xor(1), pack bf16 pairs directly.
// Row-owning layout (R12): wave w = rows w*16..+15, all 128 cols, B in
// LDS. R13: 512-thread/128-row gemm blocks. R14: int2 edge pairs.
// R17: edge_exp_z ELIMINATED — agg computes e=exp(s-m) inline in its
// gather loop (per-edge VALU, hidden under gather latency; R6/R7 showed
// only the SERIAL per-dst stats loops were harmful, not gather-side exp).
// agg<2,1> stores UNNORMALIZED partial + z01 (plain store, no atomics);
// agg<1,0> adds rel2, Z=z01+z2, normalizes + gelu. Saves the 28.8MB
// s rewrite, 4.8M atomics, 2 dispatches, 2 Zbuf zero-inits per run.
// (R18 = identical resubmit; R17 bench was an infra failure.)
// ===================================================================

// ---- MFMA input projection, 64-row blocks, single barrier ----
// K = 96 padded. B (WinT, 26.6KB) read directly from global (L1/L2-hot).
__global__ __launch_bounds__(256, 4) void input_proj_mfma(
    const float* __restrict__ x, const int* __restrict__ ast,
    const float* __restrict__ emb, const unsigned* __restrict__ WinT,
    const float* __restrict__ bin_, unsigned* __restrict__ h_bf)
{
    __shared__ unsigned Asm[64 * 52];    // 13312 B
    const int t = threadIdx.x;
    const int n0 = blockIdx.x * 64;
    const int w = t >> 6, lane = t & 63;
    const int m = lane & 15, quad = lane >> 4;
    // preload B fragments before staging (hides global latency under stage)
    bf16x8 b0[3], b1[3];
#pragma unroll
    for (int kc = 0; kc < 3; ++kc) {
        const int koff = kc * 16 + quad * 4;
        b0[kc] = *(const bf16x8*)(WinT + (size_t)(32 * w + m) * 52 + koff);
        b1[kc] = *(const bf16x8*)(WinT + (size_t)(32 * w + 16 + m) * 52 + koff);
    }
    // stage A (bf16): cols 0..63 = emb[ast[n]], 64..68 = x[n], 69..95 = 0
    for (int i = t; i < 64 * 32; i += 256) {           // emb part, branch-free
        int row = i >> 5, u = i & 31;
        float2 e = *(const float2*)(emb + (size_t)ast[n0 + row] * 64 + 2 * u);
        Asm[row * 52 + u] = bfpack(e.x, e.y);
    }
    if (t < 192) {                                     // x part: 3 uints per row
        int row = t / 3, j = t - (t / 3) * 3;
        const float* xr = x + (size_t)(n0 + row) * 5;
        float a = (j == 0) ? xr[0] : (j == 1) ? xr[2] : xr[4];
        float b = (j == 0) ? xr[1] : (j == 1) ? xr[3] : 0.f;
        Asm[row * 52 + 32 + j] = bfpack(a, b);
    }
    for (int i = t; i < 64 * 16; i += 256)             // zero pad u=35..50 (reads stop at 47)
        Asm[(i >> 4) * 52 + 35 + (i & 15)] = 0u;
    __syncthreads();
    f32x4 acc[4][2];
#pragma unroll
    for (int rt = 0; rt < 4; ++rt) { acc[rt][0] = (f32x4){0.f,0.f,0.f,0.f}; acc[rt][1] = acc[rt][0]; }
#pragma unroll
    for (int kc = 0; kc < 3; ++kc) {
        const int koff = kc * 16 + quad * 4;
#pragma unroll
        for (int rt = 0; rt < 4; ++rt) {
            bf16x8 a = *(const bf16x8*)&Asm[(rt * 16 + m) * 52 + koff];
            acc[rt][0] = __builtin_amdgcn_mfma_f32_16x16x32_bf16(a, b0[kc], acc[rt][0], 0, 0, 0);
            acc[rt][1] = __builtin_amdgcn_mfma_f32_16x16x32_bf16(a, b1[kc], acc[rt][1], 0, 0, 0);
        }
    }
    const float bv0 = bin_[32 * w + m], bv1 = bin_[32 * w + 16 + m];
    const int ub = 16 * w + 8 * (m & 1) + (m >> 1);
#pragma unroll
    for (int rt = 0; rt < 4; ++rt)
#pragma unroll
        for (int r = 0; r < 4; ++r) {
            float v0 = acc[rt][0][r] + bv0;
            float v1 = acc[rt][1][r] + bv1;
            float nv0 = __shfl_xor(v0, 1);
            float nv1 = __shfl_xor(v1, 1);
            unsigned pk = (m & 1) ? bfpack(nv1, v1) : bfpack(v0, nv0);
            h_bf[(size_t)(n0 + rt * 16 + quad * 4 + r) * 64 + ub] = pk;
        }
}

// ---- CSR build: histogram -> scan -> scatter ----
__global__ __launch_bounds__(256) void csr_hist(
    const int* __restrict__ ei0, const int* __restrict__ ei1, const int* __restrict__ ei2,
    int* __restrict__ rp)
{
    int idx = blockIdx.x * 256 + threadIdx.x;
    if (idx >= 3 * EE) return;
    int r = idx / EE, e = idx - r * EE;
    const int* ei = (r == 0) ? ei0 : ((r == 1) ? ei1 : ei2);
    atomicAdd(&rp[r * SCAN_L + ei[EE + e] + 1], 1);
}

__global__ __launch_bounds__(256) void scan1(int* __restrict__ rp, int* __restrict__ bs)
{
    __shared__ int ts[256];
    const int r = blockIdx.y;
    int* a = rp + (size_t)r * SCAN_L;
    const int base = blockIdx.x * SCAN_EPB + threadIdx.x * SCAN_E;
    int v[SCAN_E];
    int tot = 0;
#pragma unroll
    for (int j = 0; j < SCAN_E; ++j) {
        int idx = base + j;
        v[j] = (idx < SCAN_L) ? a[idx] : 0;
        tot += v[j];
    }
    ts[threadIdx.x] = tot;
    __syncthreads();
    for (int st = 1; st < 256; st <<= 1) {
        int add = (threadIdx.x >= st) ? ts[threadIdx.x - st] : 0;
        __syncthreads();
        ts[threadIdx.x] += add;
        __syncthreads();
    }
    int run = ts[threadIdx.x] - tot;
#pragma unroll
    for (int j = 0; j < SCAN_E; ++j) {
        run += v[j];
        int idx = base + j;
        if (idx < SCAN_L) a[idx] = run;
    }
    if (threadIdx.x == 255) bs[r * 128 + blockIdx.x] = ts[255];
}

__global__ __launch_bounds__(128) void scan2(int* __restrict__ bs)
{
    __shared__ int ts[128];
    const int r = blockIdx.x, t = threadIdx.x;
    int v = (t < SCAN_NB) ? bs[r * 128 + t] : 0;
    ts[t] = v;
    __syncthreads();
    for (int st = 1; st < 128; st <<= 1) {
        int add = (t >= st) ? ts[t - st] : 0;
        __syncthreads();
        ts[t] += add;
        __syncthreads();
    }
    bs[r * 128 + t] = ts[t];
}

__global__ __launch_bounds__(256) void scan3(int* __restrict__ rp, const int* __restrict__ bs)
{
    const int r = blockIdx.y;
    if (blockIdx.x == 0) return;
    const int off = bs[r * 128 + blockIdx.x - 1];
    const int base = blockIdx.x * SCAN_EPB + threadIdx.x * SCAN_E;
    int* a = rp + (size_t)r * SCAN_L;
#pragma unroll
    for (int j = 0; j < SCAN_E; ++j) {
        int idx = base + j;
        if (idx < SCAN_L) a[idx] += off;
    }
}

// ---- scatter: ONE int2 (src,dst) 8B store per edge (R14) ----
__global__ __launch_bounds__(256) void csr_scatter(
    const int* __restrict__ ei0, const int* __restrict__ ei1, const int* __restrict__ ei2,
    const int* __restrict__ rp, int* __restrict__ fill, int2* __restrict__ cpair)
{
    int idx = blockIdx.x * 256 + threadIdx.x;
    if (idx >= 3 * EE) return;
    int r = idx / EE, e = idx - r * EE;
    const int* ei = (r == 0) ? ei0 : ((r == 1) ? ei1 : ei2);
    int src = ei[e], dst = ei[EE + e];
    int pos = rp[r * SCAN_L + dst] + atomicAdd(&fill[r * NN + dst], 1);
    cpair[r * EE + pos] = make_int2(src, dst);
}

// ---- row-owning GEMM core: wave w = rows w*16..w*16+15, all 128 cols. ----
__device__ __forceinline__ void gemm_row_slot(
    const unsigned* Bsm, const bf16x8 a[4],
    int n0, int w, int m, int quad,
    const float* __restrict__ bias, unsigned* __restrict__ outp)
{
    float bo[8];
#pragma unroll
    for (int ct = 0; ct < 8; ++ct) bo[ct] = bias[ct * 16 + m];
    f32x4 acc[8];
#pragma unroll
    for (int ct = 0; ct < 8; ++ct) {
        acc[ct] = (f32x4){0.f, 0.f, 0.f, 0.f};
#pragma unroll
        for (int kc = 0; kc < 4; ++kc) {
            bf16x8 b = *(const bf16x8*)&Bsm[(ct * 16 + m) * 68 + kc * 16 + quad * 4];
            acc[ct] = __builtin_amdgcn_mfma_f32_16x16x32_bf16(a[kc], b, acc[ct], 0, 0, 0);
        }
    }
#pragma unroll
    for (int r = 0; r < 4; ++r) {
        const size_t n = (size_t)(n0 + w * 16 + quad * 4 + r);
        if (n < NN) {
#pragma unroll
            for (int cp = 0; cp < 4; ++cp) {
                float v0 = acc[2 * cp][r]     + bo[2 * cp];
                float v1 = acc[2 * cp + 1][r] + bo[2 * cp + 1];
                float nv0 = __shfl_xor(v0, 1);
                float nv1 = __shfl_xor(v1, 1);
                unsigned pk = (m & 1) ? bfpack(nv1, v1) : bfpack(v0, nv0);
                outp[n * 64 + cp * 16 + 8 * (m & 1) + (m >> 1)] = pk;
            }
        } else {
            // keep shuffles wave-uniform for inactive rows
#pragma unroll
            for (int cp = 0; cp < 4; ++cp) {
                float v0 = acc[2 * cp][r], v1 = acc[2 * cp + 1][r];
                (void)__shfl_xor(v0, 1); (void)__shfl_xor(v1, 1);
            }
        }
    }
}

// ---- 1-slot 128-row GEMM, row-owning, 512 threads (R13) ----
__global__ __launch_bounds__(512, 4) void gemm_mfma(
    const unsigned* __restrict__ in_bf, const unsigned* __restrict__ WT,
    const float* __restrict__ bias, unsigned* __restrict__ outp)
{
    __shared__ unsigned Asm[128 * 68];   // 34816 B
    __shared__ unsigned Bsm[128 * 68];   // 34816 B
    const int t = threadIdx.x;
    const int n0 = blockIdx.x * 128;
    const int w = t >> 6, lane = t & 63;
    const int m = lane & 15, quad = lane >> 4;
    for (int i = t; i < 128 * 16; i += 512) {
        int row = i >> 4, q4 = i & 15;
        size_t n = (size_t)(n0 + row); if (n >= NN) n = NN - 1;
        uint4 v = *(const uint4*)(in_bf + n * 64 + q4 * 4);
        *(uint4*)&Asm[row * 68 + q4 * 4] = v;
    }
    for (int i = t; i < 128 * 16; i += 512) {
        int row = i >> 4, q4 = i & 15;
        uint4 v = *(const uint4*)(WT + (size_t)row * 64 + q4 * 4);
        *(uint4*)&Bsm[row * 68 + q4 * 4] = v;
    }
    __syncthreads();
    bf16x8 a[4];
#pragma unroll
    for (int kc = 0; kc < 4; ++kc)
        a[kc] = *(const bf16x8*)&Asm[(w * 16 + m) * 68 + kc * 16 + quad * 4];
    gemm_row_slot(Bsm, a, n0, w, m, quad, bias, outp);
}

// ---- 2-slot 128-row GEMM, 512 threads: A staged/loaded once (R14 form) ----
__global__ __launch_bounds__(512, 4) void gemm_mfma2(
    const unsigned* __restrict__ in_bf,
    const unsigned* __restrict__ WT0, const float* __restrict__ bias0,
    unsigned* __restrict__ out0,
    const unsigned* __restrict__ WT1, const float* __restrict__ bias1,
    unsigned* __restrict__ out1)
{
    __shared__ unsigned Asm[128 * 68];
    __shared__ unsigned Bsm[128 * 68];
    const int t = threadIdx.x;
    const int n0 = blockIdx.x * 128;
    const int w = t >> 6, lane = t & 63;
    const int m = lane & 15, quad = lane >> 4;
    for (int i = t; i < 128 * 16; i += 512) {
        int row = i >> 4, q4 = i & 15;
        size_t n = (size_t)(n0 + row); if (n >= NN) n = NN - 1;
        uint4 v = *(const uint4*)(in_bf + n * 64 + q4 * 4);
        *(uint4*)&Asm[row * 68 + q4 * 4] = v;
    }
    for (int i = t; i < 128 * 16; i += 512) {
        int row = i >> 4, q4 = i & 15;
        uint4 v = *(const uint4*)(WT0 + (size_t)row * 64 + q4 * 4);
        *(uint4*)&Bsm[row * 68 + q4 * 4] = v;
    }
    __syncthreads();
    bf16x8 a[4];
#pragma unroll
    for (int kc = 0; kc < 4; ++kc)
        a[kc] = *(const bf16x8*)&Asm[(w * 16 + m) * 68 + kc * 16 + quad * 4];
    gemm_row_slot(Bsm, a, n0, w, m, quad, bias0, out0);
    __syncthreads();                       // all waves done reading B0
    for (int i = t; i < 128 * 16; i += 512) {
        int row = i >> 4, q4 = i & 15;
        uint4 v = *(const uint4*)(WT1 + (size_t)row * 64 + q4 * 4);
        *(uint4*)&Bsm[row * 68 + q4 * 4] = v;
    }
    __syncthreads();
    gemm_row_slot(Bsm, a, n0, w, m, quad, bias1, out1);
}

// ---- edge scores in CSR position order; also atomicMax the per-(dst,head)
//      running max. (src,dst) from one int2 load (R14). ----
__global__ __launch_bounds__(256) void edge_scores_csr(
    const unsigned* __restrict__ q_bf, const unsigned* __restrict__ k_bf,
    const int2* __restrict__ cpair,
    const float* __restrict__ p4, float* __restrict__ s_out,
    unsigned* __restrict__ mxi)
{
    int idx = blockIdx.x * 256 + threadIdx.x;
    if (idx >= EE * 4) return;
    int p = idx >> 2, hh = idx & 3;
    int2 pr = cpair[p];
    int src = pr.x, dst = pr.y;
    const uint4* qp = (const uint4*)(q_bf + (size_t)dst * 64 + hh * 16);
    const uint4* kp = (const uint4*)(k_bf + (size_t)src * 64 + hh * 16);
    float sum = 0.f;
#pragma unroll
    for (int i = 0; i < 4; ++i) {
        uint4 qa = qp[i], ka = kp[i];
        sum += bflo(qa.x) * bflo(ka.x) + bfhi(qa.x) * bfhi(ka.x);
        sum += bflo(qa.y) * bflo(ka.y) + bfhi(qa.y) * bfhi(ka.y);
        sum += bflo(qa.z) * bflo(ka.z) + bfhi(qa.z) * bfhi(ka.z);
        sum += bflo(qa.w) * bflo(ka.w) + bfhi(qa.w) * bfhi(ka.w);
    }
    float s = sum * p4[hh] * INV_SQRT_D;
    s_out[(size_t)p * 4 + hh] = s;
    atomicMax(&mxi[(size_t)dst * 4 + hh], fenc(s));
}

// ---- agg_reg: 16-lane-group-per-dst register aggregation (4 dsts/wave).
//      Lane sl=lane&15 owns uint4 = cols 8*sl..8*sl+7 (one head: hh=sl>>2).
//      R17: softmax exp computed INLINE (e = exp(s - m), m from mxi) and
//      partial z accumulated alongside the gather — replaces edge_exp_z.
//      FIRST=1 (rel0+rel1): store UNNORMALIZED partial As + z01 (plain
//      store). FIRST=0 (rel2): Z = z01 + z2; out = gelu((As01 + a2)/Z). ----
template<int NREL, int FIRST>
__global__ __launch_bounds__(256, 8) void agg_reg(
    const unsigned* __restrict__ pA, const unsigned* __restrict__ pB,
    const float* __restrict__ s, const int* __restrict__ rp,
    const int2* __restrict__ cpair, int ra, int rb,
    const unsigned* __restrict__ mxi, float* __restrict__ zpart,
    unsigned* __restrict__ As_g)
{
    const int lane = threadIdx.x & 63;
    const int sl = lane & 15;                 // sub-lane within dst group
    const int dst = blockIdx.x * 16 + (threadIdx.x >> 6) * 4 + (lane >> 4);
    const int hh = sl >> 2;                   // head of this lane's 8 cols
    const float mx = fdec(mxi[(size_t)dst * 4 + hh]);
    float z = 0.f;
    float a0 = 0.f, a1 = 0.f, a2 = 0.f, a3 = 0.f;
    float a4 = 0.f, a5 = 0.f, a6 = 0.f, a7 = 0.f;
#pragma unroll
    for (int q = 0; q < NREL; ++q) {
        const unsigned* pl = q ? pB : pA;
        const int r = q ? rb : ra;
        const int beg = rp[r * SCAN_L + dst];
        const int end = rp[r * SCAN_L + dst + 1];
        int p = beg;
        for (; p + 1 < end; p += 2) {
            int s0 = cpair[r * EE + p].x;
            float al0 = __expf(s[((size_t)r * EE + p) * 4 + hh] - mx);
            int s1 = cpair[r * EE + p + 1].x;
            float al1 = __expf(s[((size_t)r * EE + p + 1) * 4 + hh] - mx);
            z += al0 + al1;
            uint4 v0 = *(const uint4*)(pl + (size_t)s0 * 64 + sl * 4);
            uint4 v1 = *(const uint4*)(pl + (size_t)s1 * 64 + sl * 4);
            a0 += al0 * bflo(v0.x) + al1 * bflo(v1.x);
            a1 += al0 * bfhi(v0.x) + al1 * bfhi(v1.x);
            a2 += al0 * bflo(v0.y) + al1 * bflo(v1.y);
            a3 += al0 * bfhi(v0.y) + al1 * bfhi(v1.y);
            a4 += al0 * bflo(v0.z) + al1 * bflo(v1.z);
            a5 += al0 * bfhi(v0.z) + al1 * bfhi(v1.z);
            a6 += al0 * bflo(v0.w) + al1 * bflo(v1.w);
            a7 += al0 * bfhi(v0.w) + al1 * bfhi(v1.w);
        }
        if (p < end) {
            int s0 = cpair[r * EE + p].x;
            float al0 = __expf(s[((size_t)r * EE + p) * 4 + hh] - mx);
            z += al0;
            uint4 v0 = *(const uint4*)(pl + (size_t)s0 * 64 + sl * 4);
            a0 += al0 * bflo(v0.x); a1 += al0 * bfhi(v0.x);
            a2 += al0 * bflo(v0.y); a3 += al0 * bfhi(v0.y);
            a4 += al0 * bflo(v0.z); a5 += al0 * bfhi(v0.z);
            a6 += al0 * bflo(v0.w); a7 += al0 * bfhi(v0.w);
        }
    }
    unsigned* op = As_g + (size_t)dst * 64 + sl * 4;
    if (FIRST) {
        // store UNNORMALIZED partial (bf16 rounding is relative; |a| <= deg)
        uint4 o;
        o.x = bfpack(a0, a1); o.y = bfpack(a2, a3);
        o.z = bfpack(a4, a5); o.w = bfpack(a6, a7);
        *(uint4*)op = o;
        if ((sl & 3) == 0) zpart[(size_t)dst * 4 + hh] = z;
    } else {
        float Z = zpart[(size_t)dst * 4 + hh] + z;
        float iz = 1.f / (Z + 1e-16f);
        uint4 old = *(const uint4*)op;
        uint4 o;
        o.x = bfpack(gelu_fast((bflo(old.x) + a0) * iz), gelu_fast((bfhi(old.x) + a1) * iz));
        o.y = bfpack(gelu_fast((bflo(old.y) + a2) * iz), gelu_fast((bfhi(old.y) + a3) * iz));
        o.z = bfpack(gelu_fast((bflo(old.z) + a4) * iz), gelu_fast((bfhi(old.z) + a5) * iz));
        o.w = bfpack(gelu_fast((bflo(old.w) + a6) * iz), gelu_fast((bfhi(old.w) + a7) * iz));
        *(uint4*)op = o;
    }
}

// ---- out_ln: As(pre-gelu'd) @ Wout + bout -> skip -> LN -> h ----
// R9: wave owns 16 complete rows x 128 cols; one 16-lane butterfly per row.
// R11: B panel in LDS. R15: 512-thread/128-row blocks.
__global__ __launch_bounds__(512, 4) void out_ln(
    const unsigned* __restrict__ As_g, unsigned* __restrict__ h_bf,
    const unsigned* __restrict__ WT, const float* __restrict__ bout,
    const float* __restrict__ skipp, const float* __restrict__ lg,
    const float* __restrict__ lb)
{
    __shared__ unsigned Asm[128 * 68];   // 34816 B
    __shared__ unsigned Bsm[128 * 68];   // 34816 B
    const int t = threadIdx.x;
    const int n0 = blockIdx.x * 128;
    const int w = t >> 6, lane = t & 63;
    const int m = lane & 15, quad = lane >> 4;
    // stage A (pre-gelu'd As) and B (WT slot) to LDS, coalesced
    for (int i = t; i < 128 * 16; i += 512) {
        int row = i >> 4, q4 = i & 15;
        size_t n = (size_t)(n0 + row); if (n >= NN) n = NN - 1;
        uint4 v = *(const uint4*)(As_g + n * 64 + q4 * 4);
        *(uint4*)&Asm[row * 68 + q4 * 4] = v;
    }
    for (int i = t; i < 128 * 16; i += 512) {
        int row = i >> 4, q4 = i & 15;
        uint4 v = *(const uint4*)(WT + (size_t)row * 64 + q4 * 4);
        *(uint4*)&Bsm[row * 68 + q4 * 4] = v;
    }
    // per-col constants for this lane's 8 col-tiles (col = ct*16+m)
    float bo[8], g8[8], lb8[8];
#pragma unroll
    for (int ct = 0; ct < 8; ++ct) {
        bo[ct]  = bout[ct * 16 + m];
        g8[ct]  = lg[ct * 16 + m];
        lb8[ct] = lb[ct * 16 + m];
    }
    const float alpha = 1.f / (1.f + expf(-skipp[0]));
    const float om = 1.f - alpha;
    __syncthreads();
    // lane's A row = w*16+m (4 b128 LDS reads)
    bf16x8 a[4];
#pragma unroll
    for (int kc = 0; kc < 4; ++kc)
        a[kc] = *(const bf16x8*)&Asm[(w * 16 + m) * 68 + kc * 16 + quad * 4];
    // MFMA over 8 col-tiles; B from LDS
    f32x4 acc[8];
#pragma unroll
    for (int ct = 0; ct < 8; ++ct) {
        acc[ct] = (f32x4){0.f, 0.f, 0.f, 0.f};
#pragma unroll
        for (int kc = 0; kc < 4; ++kc) {
            bf16x8 b = *(const bf16x8*)&Bsm[(ct * 16 + m) * 68 + kc * 16 + quad * 4];
            acc[ct] = __builtin_amdgcn_mfma_f32_16x16x32_bf16(a[kc], b, acc[ct], 0, 0, 0);
        }
    }
    // o = alpha*(C+bout) + (1-alpha)*h_old; lane's output rows: w*16+quad*4+r
    const bool hi = (m & 1);
#pragma unroll
    for (int ct = 0; ct < 8; ++ct)
#pragma unroll
        for (int r = 0; r < 4; ++r) {
            size_t n = (size_t)(n0 + w * 16 + quad * 4 + r);
            if (n >= NN) n = NN - 1;            // clamped read (unused rows)
            unsigned hu = h_bf[n * 64 + ct * 8 + (m >> 1)];
            float p = hi ? bfhi(hu) : bflo(hu);
            acc[ct][r] = alpha * (acc[ct][r] + bo[ct]) + om * p;
        }
    // LN + pack + store, fully within the 16-lane group (n uniform per group)
#pragma unroll
    for (int r = 0; r < 4; ++r) {
        float po = 0.f, pq = 0.f;
#pragma unroll
        for (int ct = 0; ct < 8; ++ct) {
            float o = acc[ct][r];
            po += o;
            pq += o * o;
        }
#pragma unroll
        for (int sshf = 1; sshf < 16; sshf <<= 1) {
            po += __shfl_xor(po, sshf);
            pq += __shfl_xor(pq, sshf);
        }
        float mu = po * (1.f / 128.f);
        float var = pq * (1.f / 128.f) - mu * mu;
        float rs = rsqrtf(var + 1e-5f);
        const size_t n = (size_t)(n0 + w * 16 + quad * 4 + r);
        if (n < NN) {
#pragma unroll
            for (int cp = 0; cp < 4; ++cp) {
                float v0 = (acc[2 * cp][r]     - mu) * rs * g8[2 * cp]     + lb8[2 * cp];
                float v1 = (acc[2 * cp + 1][r] - mu) * rs * g8[2 * cp + 1] + lb8[2 * cp + 1];
                float nv0 = __shfl_xor(v0, 1);
                float nv1 = __shfl_xor(v1, 1);
                unsigned pk = (m & 1) ? bfpack(nv1, v1) : bfpack(v0, nv0);
                h_bf[n * 64 + cp * 16 + 8 * (m & 1) + (m >> 1)] = pk;
            }
        } else {
#pragma unroll
            for (int cp = 0; cp < 4; ++cp) {
                float v0 = acc[2 * cp][r], v1 = acc[2 * cp + 1][r];
                (void)__shfl_xor(v0, 1); (void)__shfl_xor(v1, 1);
            }
        }
    }
}

// ---- pool_graph: 8 chunks/graph; single-graph blocks -> register accumulate,
//      LDS reduce, 260 global atomics per block ----
__global__ __launch_bounds__(256) void pool_graph(
    const unsigned* __restrict__ h_bf, const float* __restrict__ x,
    const int* __restrict__ batch, float* __restrict__ psum, float* __restrict__ pcnt)
{
    __shared__ float ls[258];
    const int b = blockIdx.x >> 3;
    const int chunk = blockIdx.x & 7;
    const int t = threadIdx.x;
    int lo = 0, hi = NN;
    while (lo < hi) { int mid = (lo + hi) >> 1; if (batch[mid] < b) lo = mid + 1; else hi = mid; }
    const int start = lo;
    lo = 0; hi = NN;
    while (lo < hi) { int mid = (lo + hi) >> 1; if (batch[mid] < b + 1) lo = mid + 1; else hi = mid; }
    const int end = lo;
    const int len = end - start;
    const int c0 = start + (int)(((long long)len * chunk) >> 3);
    const int c1 = start + (int)(((long long)len * (chunk + 1)) >> 3);
    for (int i = t; i < 258; i += 256) ls[i] = 0.f;
    __syncthreads();
    const int c2 = t & 63;
    const int rs = t >> 6;
    float sw0 = 0.f, sw1 = 0.f, sn0 = 0.f, sn1 = 0.f, cw = 0.f, cn = 0.f;
    for (int n = c0 + rs; n < c1; n += 4) {
        float w = (x[(size_t)n * 5 + 1] > 0.f) ? 1.f : 0.f;
        unsigned u = h_bf[(size_t)n * 64 + c2];
        float h0 = bflo(u), h1 = bfhi(u);
        sw0 += w * h0; sw1 += w * h1;
        sn0 += (1.f - w) * h0; sn1 += (1.f - w) * h1;
        cw += w; cn += 1.f - w;
    }
    atomicAdd(&ls[c2 * 4 + 0], sw0);
    atomicAdd(&ls[c2 * 4 + 1], sw1);
    atomicAdd(&ls[c2 * 4 + 2], sn0);
    atomicAdd(&ls[c2 * 4 + 3], sn1);
    if (c2 == 0) { atomicAdd(&ls[256], cw); atomicAdd(&ls[257], cn); }
    __syncthreads();
    if (t < 64) {
        atomicAdd(&psum[b * 256 + 2 * t],       ls[t * 4 + 0]);
        atomicAdd(&psum[b * 256 + 2 * t + 1],   ls[t * 4 + 1]);
        atomicAdd(&psum[b * 256 + 128 + 2 * t],     ls[t * 4 + 2]);
        atomicAdd(&psum[b * 256 + 128 + 2 * t + 1], ls[t * 4 + 3]);
    } else if (t == 64) {
        atomicAdd(&pcnt[b * 2], ls[256]);
        atomicAdd(&pcnt[b * 2 + 1], ls[257]);
    }
}

// ---------------- MLP head (pool finalize fused) ----------------
__global__ __launch_bounds__(256) void head_kernel(
    const float* __restrict__ psum, const float* __restrict__ pcnt,
    const float* __restrict__ task,
    const float* __restrict__ Wtf, const float* __restrict__ btf,
    const float* __restrict__ Wc1, const float* __restrict__ bc1,
    const float* __restrict__ Wc2, const float* __restrict__ bc2,
    float* __restrict__ out)
{
    __shared__ float in_s[640];
    __shared__ float ge_s[256];
    __shared__ float hc_s[64];
    const int b = blockIdx.x, t = threadIdx.x;
    if (t < 256) {
        float cnt = pcnt[b * 2 + (t >> 7)];
        float sv = psum[b * 256 + t];
        in_s[t] = (cnt > 0.f) ? sv / fmaxf(cnt, 1.f) : 0.f;
    }
    for (int i = t; i < 384; i += 256) in_s[256 + i] = task[b * 384 + i];
    __syncthreads();
    float acc = btf[t];
    for (int i = 0; i < 640; ++i) acc += in_s[i] * Wtf[i * 256 + t];
    ge_s[t] = fmaxf(acc, 0.f);
    __syncthreads();
    if (t < 64) {
        float a2 = bc1[t];
        for (int i = 0; i < 256; ++i) a2 += ge_s[i] * Wc1[i * 64 + t];
        hc_s[t] = fmaxf(a2, 0.f);
    }
    __syncthreads();
    if (t < 64) {
        float v = hc_s[t] * Wc2[t];
#pragma unroll
        for (int off = 32; off >= 1; off >>= 1) v += __shfl_down(v, off);
        if (t == 0) out[b] = v + bc2[0];
    }
}

__global__ __launch_bounds__(256) void zero_kernel(float4* __restrict__ p, int count4)
{
    int i = blockIdx.x * 256 + threadIdx.x;
    if (i < count4) p[i] = make_float4(0.f, 0.f, 0.f, 0.f);
}

extern "C" void kernel_launch(void* const* d_in, const int* in_sizes, int n_in,
                              void* d_out, int out_size, void* d_ws, size_t ws_size,
                              hipStream_t stream)
{
    const float* x      = (const float*)d_in[0];
    const int*   ast    = (const int*)d_in[1];
    const int*   batch  = (const int*)d_in[2];
    const int*   ei[3]  = {(const int*)d_in[3], (const int*)d_in[4], (const int*)d_in[5]};
    const float* task   = (const float*)d_in[6];
    const float* emb    = (const float*)d_in[7];
    const float* Win    = (const float*)d_in[8];
    const float* bin_   = (const float*)d_in[9];
    const float* Wkqv   = (const float*)d_in[10];
    const float* bkqv   = (const float*)d_in[11];
    const float* Wk_rel = (const float*)d_in[12];
    const float* Wv_rel = (const float*)d_in[13];
    const float* p_rel  = (const float*)d_in[14];
    const float* Wout   = (const float*)d_in[15];
    const float* bout   = (const float*)d_in[16];
    const float* skip   = (const float*)d_in[17];
    const float* ln_g   = (const float*)d_in[18];
    const float* ln_b   = (const float*)d_in[19];
    const float* Wtf    = (const float*)d_in[20];
    const float* btf    = (const float*)d_in[21];
    const float* Wc1    = (const float*)d_in[22];
    const float* bc1    = (const float*)d_in[23];
    const float* Wc2    = (const float*)d_in[24];
    const float* bc2    = (const float*)d_in[25];
    float* out = (float*)d_out;
    float* ws  = (float*)d_ws;

    unsigned* hB   = (unsigned*)(ws + OFF_HB);
    unsigned* P0   = (unsigned*)(ws + OFF_P0);   // q -> vt_0 -> vt_2
    unsigned* P1   = (unsigned*)(ws + OFF_P1);   // kt_0 -> kt_1 -> vt_1
    unsigned* AS   = (unsigned*)(ws + OFF_AS);   // kt_2 -> As accumulator
    float*    sbuf = ws + OFF_S;
    int*      rp   = (int*)(ws + OFF_RP);
    int2*     cpair= (int2*)(ws + OFF_CP);
    int*      fill = (int*)(ws + OFF_P0);        // aliases P0 during CSR build only
    float*    Wf   = ws + OFF_WF;
    float*    bf   = ws + OFF_BF;
    int*      bs   = (int*)(ws + OFF_BS);
    float*    psum = ws + OFF_POOL;
    float*    pcnt = psum + (size_t)BB * 256;
    unsigned* WT   = (unsigned*)(ws + OFF_WT);   // 14 gemm slots + 2 Wout slots
    float*    zpart= ws + OFF_IZ;                // [N][4] softmax z01 partial
    unsigned* WinT = (unsigned*)(ws + OFF_WIT);
    unsigned* mxi  = (unsigned*)(ws + OFF_MX);   // [N][4] enc(max)

    fold_weights<<<14, 256, 0, stream>>>(Wkqv, bkqv, Wk_rel, Wv_rel, Wf, bf);
    pack_wt<<<14, 256, 0, stream>>>(Wf, WT);
    pack_wt<<<2, 256, 0, stream>>>(Wout, WT + (size_t)14 * 8192);
    pack_win<<<1, 256, 0, stream>>>(Win, WinT);
    input_proj_mfma<<<NN / 64, 256, 0, stream>>>(x, ast, emb, WinT, bin_, hB);

    zero_kernel<<<(600016 / 4 + 255) / 256, 256, 0, stream>>>((float4*)rp, 600016 / 4);
    zero_kernel<<<(600000 / 4 + 255) / 256, 256, 0, stream>>>((float4*)fill, 600000 / 4);
    csr_hist<<<(3 * EE + 255) / 256, 256, 0, stream>>>(ei[0], ei[1], ei[2], rp);
    scan1<<<dim3(SCAN_NB, 3), 256, 0, stream>>>(rp, bs);
    scan2<<<3, 128, 0, stream>>>(bs);
    scan3<<<dim3(SCAN_NB, 3), 256, 0, stream>>>(rp, bs);
    csr_scatter<<<(3 * EE + 255) / 256, 256, 0, stream>>>(
        ei[0], ei[1], ei[2], rp, fill, cpair);

    const int GG = (NN + 127) / 128;   // 1563 (tail-guarded)
    for (int l = 0; l < 2; ++l) {
        const size_t ls = (size_t)l * 7;   // slots: 0=q, 1..3=kt_r, 4..6=vt_r
        // zero-init softmax max (enc(-inf) = 0)
        zero_kernel<<<(800000 / 4 + 255) / 256, 256, 0, stream>>>((float4*)mxi, 800000 / 4);
        // q -> P0, kt_0 -> P1
        gemm_mfma2<<<GG, 512, 0, stream>>>(
            hB, WT + ls * 8192, bf + ls * 128, P0,
            WT + (ls + 1) * 8192, bf + (ls + 1) * 128, P1);
        edge_scores_csr<<<(EE * 4 + 255) / 256, 256, 0, stream>>>(
            P0, P1, cpair, p_rel + (size_t)l * 12, sbuf, mxi);
        // kt_1 -> P1 (kt_0 consumed), kt_2 -> AS (dead until agg)
        gemm_mfma2<<<GG, 512, 0, stream>>>(
            hB, WT + (ls + 2) * 8192, bf + (ls + 2) * 128, P1,
            WT + (ls + 3) * 8192, bf + (ls + 3) * 128, AS);
        edge_scores_csr<<<(EE * 4 + 255) / 256, 256, 0, stream>>>(
            P0, P1, cpair + (size_t)EE,
            p_rel + (size_t)(l * 3 + 1) * 4, sbuf + (size_t)EE * 4, mxi);
        edge_scores_csr<<<(EE * 4 + 255) / 256, 256, 0, stream>>>(
            P0, AS, cpair + (size_t)2 * EE,
            p_rel + (size_t)(l * 3 + 2) * 4, sbuf + (size_t)2 * EE * 4, mxi);
        // vt_0 -> P0 (q dead), vt_1 -> P1  (softmax fused into agg: R17)
        gemm_mfma2<<<GG, 512, 0, stream>>>(
            hB, WT + (ls + 4) * 8192, bf + (ls + 4) * 128, P0,
            WT + (ls + 5) * 8192, bf + (ls + 5) * 128, P1);
        agg_reg<2, 1><<<NN / 16, 256, 0, stream>>>(P0, P1, sbuf, rp, cpair, 0, 1, mxi, zpart, AS);
        gemm_mfma<<<GG, 512, 0, stream>>>(hB, WT + (ls + 6) * 8192, bf + (ls + 6) * 128, P0);
        agg_reg<1, 0><<<NN / 16, 256, 0, stream>>>(P0, P0, sbuf, rp, cpair, 2, 2, mxi, zpart, AS);
        out_ln<<<GG, 512, 0, stream>>>(
            AS, hB, WT + (size_t)(14 + l) * 8192, bout + (size_t)l * 128,
            skip + l, ln_g + (size_t)l * 128, ln_b + (size_t)l * 128);
    }

    zero_kernel<<<(16512 / 4 + 255) / 256, 256, 0, stream>>>((float4*)psum, 16512 / 4);
    pool_graph<<<BB * 8, 256, 0, stream>>>(hB, x, batch, psum, pcnt);
    head_kernel<<<BB, 256, 0, stream>>>(psum, pcnt, task, Wtf, btf, Wc1, bc1, Wc2, bc2, out);
}

// Round 19
// 1001.590 us; speedup vs baseline: 1.1801x; 1.0681x over previous
//
#include <hip/hip_runtime.h>
#include <math.h>

// Problem constants (match reference)
#define NN 200000
#define EE 300000
#define BB 64
#define INV_SQRT_D 0.17677669529663687f

// ---- workspace layout in 4-byte words. Total ≈ 59.19M words = 236.7 MB.
#define OFF_HB   ((size_t)0)                    // [N][64] uint (bf16x2) node features
#define OFF_P0   ((size_t)12800000)             // [N][64] uint: q, then vt_0, then vt_2
#define OFF_P1   ((size_t)25600000)             // [N][64] uint: kt_0 -> kt_1 -> vt_1
#define OFF_AS   ((size_t)38400000)             // [N][64] uint: kt_2 -> As accumulator
#define OFF_S    ((size_t)51200000)             // [3][E][4] f32 RAW scores (CSR order)
#define OFF_RP   ((size_t)54800000)             // [3][N+1] int rowptr (padded 600016)
#define OFF_CP   ((size_t)55400016)             // [3][E] int2 (src,dst) per CSR position
#define OFF_WF   ((size_t)57200016)             // 14 x [128][128] f32 folded weights
#define OFF_BF   ((size_t)57429392)             // 14 x [128] f32 folded bias
#define OFF_BS   ((size_t)57431184)             // scan block sums 3*128 int
#define OFF_POOL ((size_t)57431568)             // psum [B][256] + pcnt [B][2] (16512)
#define OFF_WT   ((size_t)57448080)             // 16 x [128][64] uint packed W^T
#define OFF_IZ   ((size_t)57579152)             // [N][4] f32 softmax z01 partial
#define OFF_WIT  ((size_t)58379152)             // [128][52] uint packed Win^T
#define OFF_MX   ((size_t)58385808)             // [N][4] uint enc(max) (atomicMax)

#define SCAN_L   (NN + 1)
#define SCAN_E   8
#define SCAN_EPB (256 * SCAN_E)                          // 2048
#define SCAN_NB  ((SCAN_L + SCAN_EPB - 1) / SCAN_EPB)    // 98

typedef __attribute__((ext_vector_type(8))) short bf16x8;
typedef __attribute__((ext_vector_type(4))) float f32x4;

// Fast gelu: A&S 7.1.26 rational erf approx, |eps| <= 1.5e-7 absolute.
__device__ __forceinline__ float gelu_fast(float v) {
    float x = fabsf(v) * 0.70710678118654752f;
    float t = 1.0f / fmaf(0.3275911f, x, 1.0f);
    float p = fmaf(fmaf(fmaf(fmaf(1.061405429f, t, -1.453152027f), t, 1.421413741f),
                        t, -0.284496736f), t, 0.254829592f) * t;
    float er = 1.0f - p * __expf(-x * x);
    er = copysignf(er, v);
    return 0.5f * v * (1.0f + er);
}
__device__ __forceinline__ float bflo(unsigned u) { return __uint_as_float(u << 16); }
__device__ __forceinline__ float bfhi(unsigned u) { return __uint_as_float(u & 0xffff0000u); }
__device__ __forceinline__ unsigned bfpack(float a, float b) {
    unsigned ua = __float_as_uint(a); ua += 0x7fffu + ((ua >> 16) & 1u);
    unsigned ub = __float_as_uint(b); ub += 0x7fffu + ((ub >> 16) & 1u);
    return (ua >> 16) | (ub & 0xffff0000u);
}
// Monotonic float<->uint encoding for atomicMax on floats.
__device__ __forceinline__ unsigned fenc(float f) {
    unsigned u = __float_as_uint(f);
    return (u & 0x80000000u) ? ~u : (u | 0x80000000u);
}
__device__ __forceinline__ float fdec(unsigned e) {
    return __uint_as_float((e & 0x80000000u) ? (e & 0x7fffffffu) : ~e);
}

// ---- fold weights. 14 slots: per layer l: [l*7+0]=q copy, [l*7+1+r]=k@Wk_rel[r],
//      [l*7+4+r]=v@Wv_rel[r].  kqv split order is k|q|v (cols 0/128/256).
__global__ __launch_bounds__(256) void fold_weights(
    const float* __restrict__ Wkqv, const float* __restrict__ bkqv,
    const float* __restrict__ Wk_rel, const float* __restrict__ Wv_rel,
    float* __restrict__ Wf, float* __restrict__ bf)
{
    __shared__ float Wr[4096];
    const int b = blockIdx.x, t = threadIdx.x;
    const int l = b / 7, s = b % 7;
    const float* Wq = Wkqv + (size_t)l * 49152;   // [128][384]
    if (s == 0) {
        for (int i = t; i < 16384; i += 256) {
            int kk = i >> 7, c = i & 127;
            Wf[(size_t)b * 16384 + i] = Wq[kk * 384 + 128 + c];
        }
        if (t < 128) bf[b * 128 + t] = bkqv[l * 384 + 128 + t];
    } else {
        const int side = (s - 1) / 3, r = (s - 1) % 3;
        const int off = side ? 256 : 0;
        const float* Wrel = (side ? Wv_rel : Wk_rel) + (size_t)(l * 3 + r) * 4096;
        for (int i = t; i < 4096; i += 256) Wr[i] = Wrel[i];
        __syncthreads();
        for (int i = t; i < 16384; i += 256) {
            int kk = i >> 7, c = i & 127, hh = c >> 5, f = c & 31;
            const float* wrow = Wq + kk * 384 + off + hh * 32;
            const float* wr = Wr + hh * 1024 + f;
            float sum = 0.f;
#pragma unroll
            for (int d = 0; d < 32; ++d) sum += wrow[d] * wr[d * 32];
            Wf[(size_t)b * 16384 + i] = sum;
        }
        if (t < 128) {
            int hh = t >> 5, f = t & 31;
            float sum = 0.f;
#pragma unroll
            for (int d = 0; d < 32; ++d)
                sum += bkqv[l * 384 + off + hh * 32 + d] * Wr[hh * 1024 + d * 32 + f];
            bf[b * 128 + t] = sum;
        }
    }
}

// ---- pack W -> bf16x2-packed W^T: WT[slot][c][w] = (W[2w][c], W[2w+1][c]) ----
__global__ __launch_bounds__(256) void pack_wt(
    const float* __restrict__ W, unsigned* __restrict__ WT)
{
    const int slot = blockIdx.x, t = threadIdx.x;
    const float* Ws = W + (size_t)slot * 16384;
    unsigned* WTs = WT + (size_t)slot * 8192;
    for (int i = t; i < 8192; i += 256) {
        int c = i >> 6, w = i & 63;
        WTs[i] = bfpack(Ws[(size_t)(2 * w) * 128 + c], Ws[(size_t)(2 * w + 1) * 128 + c]);
    }
}

// ---- pack Win (69x128 f32) -> WinT bf16 [128][52] ----
__global__ __launch_bounds__(256) void pack_win(
    const float* __restrict__ Win, unsigned* __restrict__ WinT)
{
    const int t = threadIdx.x;
    for (int i = t; i < 128 * 52; i += 256) {
        int c = i / 52, u = i - c * 52;
        unsigned v = 0;
        if (u < 34) {
            v = bfpack(Win[(size_t)(2 * u) * 128 + c], Win[(size_t)(2 * u + 1) * 128 + c]);
        } else if (u == 34) {
            v = bfpack(Win[(size_t)68 * 128 + c], 0.f);
        }
        WinT[i] = v;
    }
}

// ===================================================================
// MFMA C layout (16x16x32): col=lane&15, row=(lane>>4)*4+reg.
// Row-owning layout (R12): wave w = rows w*16..+15, all 128 cols.
// R19: A panel LDS-staging ELIMINATED in gemm/out_ln — in the
// row-owning layout each lane's a[kc] is PRIVATE (its own row), so it
// loads directly from global (4x16B/lane; per wave each load touches 16
// fully-consumed 64B lines). Halves LDS (69.6->34.8KB) -> 4 blocks/CU
// (32 waves, 2x residency). B stays in LDS (shared by all waves).
// Bitwise-identical math. R17/18: softmax fused into agg.
// ===================================================================

// ---- MFMA input projection, 64-row blocks, single barrier ----
__global__ __launch_bounds__(256, 4) void input_proj_mfma(
    const float* __restrict__ x, const int* __restrict__ ast,
    const float* __restrict__ emb, const unsigned* __restrict__ WinT,
    const float* __restrict__ bin_, unsigned* __restrict__ h_bf)
{
    __shared__ unsigned Asm[64 * 52];    // 13312 B
    const int t = threadIdx.x;
    const int n0 = blockIdx.x * 64;
    const int w = t >> 6, lane = t & 63;
    const int m = lane & 15, quad = lane >> 4;
    bf16x8 b0[3], b1[3];
#pragma unroll
    for (int kc = 0; kc < 3; ++kc) {
        const int koff = kc * 16 + quad * 4;
        b0[kc] = *(const bf16x8*)(WinT + (size_t)(32 * w + m) * 52 + koff);
        b1[kc] = *(const bf16x8*)(WinT + (size_t)(32 * w + 16 + m) * 52 + koff);
    }
    for (int i = t; i < 64 * 32; i += 256) {
        int row = i >> 5, u = i & 31;
        float2 e = *(const float2*)(emb + (size_t)ast[n0 + row] * 64 + 2 * u);
        Asm[row * 52 + u] = bfpack(e.x, e.y);
    }
    if (t < 192) {
        int row = t / 3, j = t - (t / 3) * 3;
        const float* xr = x + (size_t)(n0 + row) * 5;
        float a = (j == 0) ? xr[0] : (j == 1) ? xr[2] : xr[4];
        float b = (j == 0) ? xr[1] : (j == 1) ? xr[3] : 0.f;
        Asm[row * 52 + 32 + j] = bfpack(a, b);
    }
    for (int i = t; i < 64 * 16; i += 256)
        Asm[(i >> 4) * 52 + 35 + (i & 15)] = 0u;
    __syncthreads();
    f32x4 acc[4][2];
#pragma unroll
    for (int rt = 0; rt < 4; ++rt) { acc[rt][0] = (f32x4){0.f,0.f,0.f,0.f}; acc[rt][1] = acc[rt][0]; }
#pragma unroll
    for (int kc = 0; kc < 3; ++kc) {
        const int koff = kc * 16 + quad * 4;
#pragma unroll
        for (int rt = 0; rt < 4; ++rt) {
            bf16x8 a = *(const bf16x8*)&Asm[(rt * 16 + m) * 52 + koff];
            acc[rt][0] = __builtin_amdgcn_mfma_f32_16x16x32_bf16(a, b0[kc], acc[rt][0], 0, 0, 0);
            acc[rt][1] = __builtin_amdgcn_mfma_f32_16x16x32_bf16(a, b1[kc], acc[rt][1], 0, 0, 0);
        }
    }
    const float bv0 = bin_[32 * w + m], bv1 = bin_[32 * w + 16 + m];
    const int ub = 16 * w + 8 * (m & 1) + (m >> 1);
#pragma unroll
    for (int rt = 0; rt < 4; ++rt)
#pragma unroll
        for (int r = 0; r < 4; ++r) {
            float v0 = acc[rt][0][r] + bv0;
            float v1 = acc[rt][1][r] + bv1;
            float nv0 = __shfl_xor(v0, 1);
            float nv1 = __shfl_xor(v1, 1);
            unsigned pk = (m & 1) ? bfpack(nv1, v1) : bfpack(v0, nv0);
            h_bf[(size_t)(n0 + rt * 16 + quad * 4 + r) * 64 + ub] = pk;
        }
}

// ---- CSR build: histogram -> scan -> scatter ----
__global__ __launch_bounds__(256) void csr_hist(
    const int* __restrict__ ei0, const int* __restrict__ ei1, const int* __restrict__ ei2,
    int* __restrict__ rp)
{
    int idx = blockIdx.x * 256 + threadIdx.x;
    if (idx >= 3 * EE) return;
    int r = idx / EE, e = idx - r * EE;
    const int* ei = (r == 0) ? ei0 : ((r == 1) ? ei1 : ei2);
    atomicAdd(&rp[r * SCAN_L + ei[EE + e] + 1], 1);
}

__global__ __launch_bounds__(256) void scan1(int* __restrict__ rp, int* __restrict__ bs)
{
    __shared__ int ts[256];
    const int r = blockIdx.y;
    int* a = rp + (size_t)r * SCAN_L;
    const int base = blockIdx.x * SCAN_EPB + threadIdx.x * SCAN_E;
    int v[SCAN_E];
    int tot = 0;
#pragma unroll
    for (int j = 0; j < SCAN_E; ++j) {
        int idx = base + j;
        v[j] = (idx < SCAN_L) ? a[idx] : 0;
        tot += v[j];
    }
    ts[threadIdx.x] = tot;
    __syncthreads();
    for (int st = 1; st < 256; st <<= 1) {
        int add = (threadIdx.x >= st) ? ts[threadIdx.x - st] : 0;
        __syncthreads();
        ts[threadIdx.x] += add;
        __syncthreads();
    }
    int run = ts[threadIdx.x] - tot;
#pragma unroll
    for (int j = 0; j < SCAN_E; ++j) {
        run += v[j];
        int idx = base + j;
        if (idx < SCAN_L) a[idx] = run;
    }
    if (threadIdx.x == 255) bs[r * 128 + blockIdx.x] = ts[255];
}

__global__ __launch_bounds__(128) void scan2(int* __restrict__ bs)
{
    __shared__ int ts[128];
    const int r = blockIdx.x, t = threadIdx.x;
    int v = (t < SCAN_NB) ? bs[r * 128 + t] : 0;
    ts[t] = v;
    __syncthreads();
    for (int st = 1; st < 128; st <<= 1) {
        int add = (t >= st) ? ts[t - st] : 0;
        __syncthreads();
        ts[t] += add;
        __syncthreads();
    }
    bs[r * 128 + t] = ts[t];
}

__global__ __launch_bounds__(256) void scan3(int* __restrict__ rp, const int* __restrict__ bs)
{
    const int r = blockIdx.y;
    if (blockIdx.x == 0) return;
    const int off = bs[r * 128 + blockIdx.x - 1];
    const int base = blockIdx.x * SCAN_EPB + threadIdx.x * SCAN_E;
    int* a = rp + (size_t)r * SCAN_L;
#pragma unroll
    for (int j = 0; j < SCAN_E; ++j) {
        int idx = base + j;
        if (idx < SCAN_L) a[idx] += off;
    }
}

// ---- scatter: ONE int2 (src,dst) 8B store per edge (R14) ----
__global__ __launch_bounds__(256) void csr_scatter(
    const int* __restrict__ ei0, const int* __restrict__ ei1, const int* __restrict__ ei2,
    const int* __restrict__ rp, int* __restrict__ fill, int2* __restrict__ cpair)
{
    int idx = blockIdx.x * 256 + threadIdx.x;
    if (idx >= 3 * EE) return;
    int r = idx / EE, e = idx - r * EE;
    const int* ei = (r == 0) ? ei0 : ((r == 1) ? ei1 : ei2);
    int src = ei[e], dst = ei[EE + e];
    int pos = rp[r * SCAN_L + dst] + atomicAdd(&fill[r * NN + dst], 1);
    cpair[r * EE + pos] = make_int2(src, dst);
}

// ---- load this lane's private A row fragments directly from global (R19) ----
__device__ __forceinline__ void loadA_row(
    const unsigned* __restrict__ in_bf, size_t nrow, int quad, bf16x8 a[4])
{
#pragma unroll
    for (int kc = 0; kc < 4; ++kc)
        a[kc] = *(const bf16x8*)(in_bf + nrow * 64 + kc * 16 + quad * 4);
}

// ---- row-owning GEMM core: wave w = rows w*16..w*16+15, all 128 cols. ----
__device__ __forceinline__ void gemm_row_slot(
    const unsigned* Bsm, const bf16x8 a[4],
    int n0, int w, int m, int quad,
    const float* __restrict__ bias, unsigned* __restrict__ outp)
{
    float bo[8];
#pragma unroll
    for (int ct = 0; ct < 8; ++ct) bo[ct] = bias[ct * 16 + m];
    f32x4 acc[8];
#pragma unroll
    for (int ct = 0; ct < 8; ++ct) {
        acc[ct] = (f32x4){0.f, 0.f, 0.f, 0.f};
#pragma unroll
        for (int kc = 0; kc < 4; ++kc) {
            bf16x8 b = *(const bf16x8*)&Bsm[(ct * 16 + m) * 68 + kc * 16 + quad * 4];
            acc[ct] = __builtin_amdgcn_mfma_f32_16x16x32_bf16(a[kc], b, acc[ct], 0, 0, 0);
        }
    }
#pragma unroll
    for (int r = 0; r < 4; ++r) {
        const size_t n = (size_t)(n0 + w * 16 + quad * 4 + r);
        if (n < NN) {
#pragma unroll
            for (int cp = 0; cp < 4; ++cp) {
                float v0 = acc[2 * cp][r]     + bo[2 * cp];
                float v1 = acc[2 * cp + 1][r] + bo[2 * cp + 1];
                float nv0 = __shfl_xor(v0, 1);
                float nv1 = __shfl_xor(v1, 1);
                unsigned pk = (m & 1) ? bfpack(nv1, v1) : bfpack(v0, nv0);
                outp[n * 64 + cp * 16 + 8 * (m & 1) + (m >> 1)] = pk;
            }
        } else {
#pragma unroll
            for (int cp = 0; cp < 4; ++cp) {
                float v0 = acc[2 * cp][r], v1 = acc[2 * cp + 1][r];
                (void)__shfl_xor(v0, 1); (void)__shfl_xor(v1, 1);
            }
        }
    }
}

// ---- 1-slot 128-row GEMM, 512 threads, A direct-from-global (R19) ----
__global__ __launch_bounds__(512, 4) void gemm_mfma(
    const unsigned* __restrict__ in_bf, const unsigned* __restrict__ WT,
    const float* __restrict__ bias, unsigned* __restrict__ outp)
{
    __shared__ unsigned Bsm[128 * 68];   // 34816 B (A no longer staged)
    const int t = threadIdx.x;
    const int n0 = blockIdx.x * 128;
    const int w = t >> 6, lane = t & 63;
    const int m = lane & 15, quad = lane >> 4;
    size_t arow = (size_t)(n0 + w * 16 + m); if (arow >= NN) arow = NN - 1;
    bf16x8 a[4];
    loadA_row(in_bf, arow, quad, a);       // private row, issues before barrier
    for (int i = t; i < 128 * 16; i += 512) {
        int row = i >> 4, q4 = i & 15;
        uint4 v = *(const uint4*)(WT + (size_t)row * 64 + q4 * 4);
        *(uint4*)&Bsm[row * 68 + q4 * 4] = v;
    }
    __syncthreads();
    gemm_row_slot(Bsm, a, n0, w, m, quad, bias, outp);
}

// ---- 2-slot 128-row GEMM, 512 threads, A direct-from-global (R19) ----
__global__ __launch_bounds__(512, 4) void gemm_mfma2(
    const unsigned* __restrict__ in_bf,
    const unsigned* __restrict__ WT0, const float* __restrict__ bias0,
    unsigned* __restrict__ out0,
    const unsigned* __restrict__ WT1, const float* __restrict__ bias1,
    unsigned* __restrict__ out1)
{
    __shared__ unsigned Bsm[128 * 68];   // 34816 B
    const int t = threadIdx.x;
    const int n0 = blockIdx.x * 128;
    const int w = t >> 6, lane = t & 63;
    const int m = lane & 15, quad = lane >> 4;
    size_t arow = (size_t)(n0 + w * 16 + m); if (arow >= NN) arow = NN - 1;
    bf16x8 a[4];
    loadA_row(in_bf, arow, quad, a);
    for (int i = t; i < 128 * 16; i += 512) {
        int row = i >> 4, q4 = i & 15;
        uint4 v = *(const uint4*)(WT0 + (size_t)row * 64 + q4 * 4);
        *(uint4*)&Bsm[row * 68 + q4 * 4] = v;
    }
    __syncthreads();
    gemm_row_slot(Bsm, a, n0, w, m, quad, bias0, out0);
    __syncthreads();                       // all waves done reading B0
    for (int i = t; i < 128 * 16; i += 512) {
        int row = i >> 4, q4 = i & 15;
        uint4 v = *(const uint4*)(WT1 + (size_t)row * 64 + q4 * 4);
        *(uint4*)&Bsm[row * 68 + q4 * 4] = v;
    }
    __syncthreads();
    gemm_row_slot(Bsm, a, n0, w, m, quad, bias1, out1);
}

// ---- edge scores in CSR position order; also atomicMax per-(dst,head) max ----
__global__ __launch_bounds__(256) void edge_scores_csr(
    const unsigned* __restrict__ q_bf, const unsigned* __restrict__ k_bf,
    const int2* __restrict__ cpair,
    const float* __restrict__ p4, float* __restrict__ s_out,
    unsigned* __restrict__ mxi)
{
    int idx = blockIdx.x * 256 + threadIdx.x;
    if (idx >= EE * 4) return;
    int p = idx >> 2, hh = idx & 3;
    int2 pr = cpair[p];
    int src = pr.x, dst = pr.y;
    const uint4* qp = (const uint4*)(q_bf + (size_t)dst * 64 + hh * 16);
    const uint4* kp = (const uint4*)(k_bf + (size_t)src * 64 + hh * 16);
    float sum = 0.f;
#pragma unroll
    for (int i = 0; i < 4; ++i) {
        uint4 qa = qp[i], ka = kp[i];
        sum += bflo(qa.x) * bflo(ka.x) + bfhi(qa.x) * bfhi(ka.x);
        sum += bflo(qa.y) * bflo(ka.y) + bfhi(qa.y) * bfhi(ka.y);
        sum += bflo(qa.z) * bflo(ka.z) + bfhi(qa.z) * bfhi(ka.z);
        sum += bflo(qa.w) * bflo(ka.w) + bfhi(qa.w) * bfhi(ka.w);
    }
    float s = sum * p4[hh] * INV_SQRT_D;
    s_out[(size_t)p * 4 + hh] = s;
    atomicMax(&mxi[(size_t)dst * 4 + hh], fenc(s));
}

// ---- agg_reg: 16-lane-group-per-dst aggregation, softmax fused (R17). ----
template<int NREL, int FIRST>
__global__ __launch_bounds__(256, 8) void agg_reg(
    const unsigned* __restrict__ pA, const unsigned* __restrict__ pB,
    const float* __restrict__ s, const int* __restrict__ rp,
    const int2* __restrict__ cpair, int ra, int rb,
    const unsigned* __restrict__ mxi, float* __restrict__ zpart,
    unsigned* __restrict__ As_g)
{
    const int lane = threadIdx.x & 63;
    const int sl = lane & 15;                 // sub-lane within dst group
    const int dst = blockIdx.x * 16 + (threadIdx.x >> 6) * 4 + (lane >> 4);
    const int hh = sl >> 2;                   // head of this lane's 8 cols
    const float mx = fdec(mxi[(size_t)dst * 4 + hh]);
    float z = 0.f;
    float a0 = 0.f, a1 = 0.f, a2 = 0.f, a3 = 0.f;
    float a4 = 0.f, a5 = 0.f, a6 = 0.f, a7 = 0.f;
#pragma unroll
    for (int q = 0; q < NREL; ++q) {
        const unsigned* pl = q ? pB : pA;
        const int r = q ? rb : ra;
        const int beg = rp[r * SCAN_L + dst];
        const int end = rp[r * SCAN_L + dst + 1];
        int p = beg;
        for (; p + 1 < end; p += 2) {
            int s0 = cpair[r * EE + p].x;
            float al0 = __expf(s[((size_t)r * EE + p) * 4 + hh] - mx);
            int s1 = cpair[r * EE + p + 1].x;
            float al1 = __expf(s[((size_t)r * EE + p + 1) * 4 + hh] - mx);
            z += al0 + al1;
            uint4 v0 = *(const uint4*)(pl + (size_t)s0 * 64 + sl * 4);
            uint4 v1 = *(const uint4*)(pl + (size_t)s1 * 64 + sl * 4);
            a0 += al0 * bflo(v0.x) + al1 * bflo(v1.x);
            a1 += al0 * bfhi(v0.x) + al1 * bfhi(v1.x);
            a2 += al0 * bflo(v0.y) + al1 * bflo(v1.y);
            a3 += al0 * bfhi(v0.y) + al1 * bfhi(v1.y);
            a4 += al0 * bflo(v0.z) + al1 * bflo(v1.z);
            a5 += al0 * bfhi(v0.z) + al1 * bfhi(v1.z);
            a6 += al0 * bflo(v0.w) + al1 * bflo(v1.w);
            a7 += al0 * bfhi(v0.w) + al1 * bfhi(v1.w);
        }
        if (p < end) {
            int s0 = cpair[r * EE + p].x;
            float al0 = __expf(s[((size_t)r * EE + p) * 4 + hh] - mx);
            z += al0;
            uint4 v0 = *(const uint4*)(pl + (size_t)s0 * 64 + sl * 4);
            a0 += al0 * bflo(v0.x); a1 += al0 * bfhi(v0.x);
            a2 += al0 * bflo(v0.y); a3 += al0 * bfhi(v0.y);
            a4 += al0 * bflo(v0.z); a5 += al0 * bfhi(v0.z);
            a6 += al0 * bflo(v0.w); a7 += al0 * bfhi(v0.w);
        }
    }
    unsigned* op = As_g + (size_t)dst * 64 + sl * 4;
    if (FIRST) {
        uint4 o;
        o.x = bfpack(a0, a1); o.y = bfpack(a2, a3);
        o.z = bfpack(a4, a5); o.w = bfpack(a6, a7);
        *(uint4*)op = o;
        if ((sl & 3) == 0) zpart[(size_t)dst * 4 + hh] = z;
    } else {
        float Z = zpart[(size_t)dst * 4 + hh] + z;
        float iz = 1.f / (Z + 1e-16f);
        uint4 old = *(const uint4*)op;
        uint4 o;
        o.x = bfpack(gelu_fast((bflo(old.x) + a0) * iz), gelu_fast((bfhi(old.x) + a1) * iz));
        o.y = bfpack(gelu_fast((bflo(old.y) + a2) * iz), gelu_fast((bfhi(old.y) + a3) * iz));
        o.z = bfpack(gelu_fast((bflo(old.z) + a4) * iz), gelu_fast((bfhi(old.z) + a5) * iz));
        o.w = bfpack(gelu_fast((bflo(old.w) + a6) * iz), gelu_fast((bfhi(old.w) + a7) * iz));
        *(uint4*)op = o;
    }
}

// ---- out_ln: As(pre-gelu'd) @ Wout + bout -> skip -> LN -> h ----
// R19: A direct-from-global (private rows); LDS holds only B. 512 threads.
__global__ __launch_bounds__(512, 4) void out_ln(
    const unsigned* __restrict__ As_g, unsigned* __restrict__ h_bf,
    const unsigned* __restrict__ WT, const float* __restrict__ bout,
    const float* __restrict__ skipp, const float* __restrict__ lg,
    const float* __restrict__ lb)
{
    __shared__ unsigned Bsm[128 * 68];   // 34816 B
    const int t = threadIdx.x;
    const int n0 = blockIdx.x * 128;
    const int w = t >> 6, lane = t & 63;
    const int m = lane & 15, quad = lane >> 4;
    size_t arow = (size_t)(n0 + w * 16 + m); if (arow >= NN) arow = NN - 1;
    bf16x8 a[4];
    loadA_row(As_g, arow, quad, a);
    for (int i = t; i < 128 * 16; i += 512) {
        int row = i >> 4, q4 = i & 15;
        uint4 v = *(const uint4*)(WT + (size_t)row * 64 + q4 * 4);
        *(uint4*)&Bsm[row * 68 + q4 * 4] = v;
    }
    float bo[8], g8[8], lb8[8];
#pragma unroll
    for (int ct = 0; ct < 8; ++ct) {
        bo[ct]  = bout[ct * 16 + m];
        g8[ct]  = lg[ct * 16 + m];
        lb8[ct] = lb[ct * 16 + m];
    }
    const float alpha = 1.f / (1.f + expf(-skipp[0]));
    const float om = 1.f - alpha;
    __syncthreads();
    f32x4 acc[8];
#pragma unroll
    for (int ct = 0; ct < 8; ++ct) {
        acc[ct] = (f32x4){0.f, 0.f, 0.f, 0.f};
#pragma unroll
        for (int kc = 0; kc < 4; ++kc) {
            bf16x8 b = *(const bf16x8*)&Bsm[(ct * 16 + m) * 68 + kc * 16 + quad * 4];
            acc[ct] = __builtin_amdgcn_mfma_f32_16x16x32_bf16(a[kc], b, acc[ct], 0, 0, 0);
        }
    }
    const bool hi = (m & 1);
#pragma unroll
    for (int ct = 0; ct < 8; ++ct)
#pragma unroll
        for (int r = 0; r < 4; ++r) {
            size_t n = (size_t)(n0 + w * 16 + quad * 4 + r);
            if (n >= NN) n = NN - 1;            // clamped read (unused rows)
            unsigned hu = h_bf[n * 64 + ct * 8 + (m >> 1)];
            float p = hi ? bfhi(hu) : bflo(hu);
            acc[ct][r] = alpha * (acc[ct][r] + bo[ct]) + om * p;
        }
#pragma unroll
    for (int r = 0; r < 4; ++r) {
        float po = 0.f, pq = 0.f;
#pragma unroll
        for (int ct = 0; ct < 8; ++ct) {
            float o = acc[ct][r];
            po += o;
            pq += o * o;
        }
#pragma unroll
        for (int sshf = 1; sshf < 16; sshf <<= 1) {
            po += __shfl_xor(po, sshf);
            pq += __shfl_xor(pq, sshf);
        }
        float mu = po * (1.f / 128.f);
        float var = pq * (1.f / 128.f) - mu * mu;
        float rs = rsqrtf(var + 1e-5f);
        const size_t n = (size_t)(n0 + w * 16 + quad * 4 + r);
        if (n < NN) {
#pragma unroll
            for (int cp = 0; cp < 4; ++cp) {
                float v0 = (acc[2 * cp][r]     - mu) * rs * g8[2 * cp]     + lb8[2 * cp];
                float v1 = (acc[2 * cp + 1][r] - mu) * rs * g8[2 * cp + 1] + lb8[2 * cp + 1];
                float nv0 = __shfl_xor(v0, 1);
                float nv1 = __shfl_xor(v1, 1);
                unsigned pk = (m & 1) ? bfpack(nv1, v1) : bfpack(v0, nv0);
                h_bf[n * 64 + cp * 16 + 8 * (m & 1) + (m >> 1)] = pk;
            }
        } else {
#pragma unroll
            for (int cp = 0; cp < 4; ++cp) {
                float v0 = acc[2 * cp][r], v1 = acc[2 * cp + 1][r];
                (void)__shfl_xor(v0, 1); (void)__shfl_xor(v1, 1);
            }
        }
    }
}

// ---- pool_graph: 8 chunks/graph ----
__global__ __launch_bounds__(256) void pool_graph(
    const unsigned* __restrict__ h_bf, const float* __restrict__ x,
    const int* __restrict__ batch, float* __restrict__ psum, float* __restrict__ pcnt)
{
    __shared__ float ls[258];
    const int b = blockIdx.x >> 3;
    const int chunk = blockIdx.x & 7;
    const int t = threadIdx.x;
    int lo = 0, hi = NN;
    while (lo < hi) { int mid = (lo + hi) >> 1; if (batch[mid] < b) lo = mid + 1; else hi = mid; }
    const int start = lo;
    lo = 0; hi = NN;
    while (lo < hi) { int mid = (lo + hi) >> 1; if (batch[mid] < b + 1) lo = mid + 1; else hi = mid; }
    const int end = lo;
    const int len = end - start;
    const int c0 = start + (int)(((long long)len * chunk) >> 3);
    const int c1 = start + (int)(((long long)len * (chunk + 1)) >> 3);
    for (int i = t; i < 258; i += 256) ls[i] = 0.f;
    __syncthreads();
    const int c2 = t & 63;
    const int rs = t >> 6;
    float sw0 = 0.f, sw1 = 0.f, sn0 = 0.f, sn1 = 0.f, cw = 0.f, cn = 0.f;
    for (int n = c0 + rs; n < c1; n += 4) {
        float w = (x[(size_t)n * 5 + 1] > 0.f) ? 1.f : 0.f;
        unsigned u = h_bf[(size_t)n * 64 + c2];
        float h0 = bflo(u), h1 = bfhi(u);
        sw0 += w * h0; sw1 += w * h1;
        sn0 += (1.f - w) * h0; sn1 += (1.f - w) * h1;
        cw += w; cn += 1.f - w;
    }
    atomicAdd(&ls[c2 * 4 + 0], sw0);
    atomicAdd(&ls[c2 * 4 + 1], sw1);
    atomicAdd(&ls[c2 * 4 + 2], sn0);
    atomicAdd(&ls[c2 * 4 + 3], sn1);
    if (c2 == 0) { atomicAdd(&ls[256], cw); atomicAdd(&ls[257], cn); }
    __syncthreads();
    if (t < 64) {
        atomicAdd(&psum[b * 256 + 2 * t],       ls[t * 4 + 0]);
        atomicAdd(&psum[b * 256 + 2 * t + 1],   ls[t * 4 + 1]);
        atomicAdd(&psum[b * 256 + 128 + 2 * t],     ls[t * 4 + 2]);
        atomicAdd(&psum[b * 256 + 128 + 2 * t + 1], ls[t * 4 + 3]);
    } else if (t == 64) {
        atomicAdd(&pcnt[b * 2], ls[256]);
        atomicAdd(&pcnt[b * 2 + 1], ls[257]);
    }
}

// ---------------- MLP head (pool finalize fused) ----------------
__global__ __launch_bounds__(256) void head_kernel(
    const float* __restrict__ psum, const float* __restrict__ pcnt,
    const float* __restrict__ task,
    const float* __restrict__ Wtf, const float* __restrict__ btf,
    const float* __restrict__ Wc1, const float* __restrict__ bc1,
    const float* __restrict__ Wc2, const float* __restrict__ bc2,
    float* __restrict__ out)
{
    __shared__ float in_s[640];
    __shared__ float ge_s[256];
    __shared__ float hc_s[64];
    const int b = blockIdx.x, t = threadIdx.x;
    if (t < 256) {
        float cnt = pcnt[b * 2 + (t >> 7)];
        float sv = psum[b * 256 + t];
        in_s[t] = (cnt > 0.f) ? sv / fmaxf(cnt, 1.f) : 0.f;
    }
    for (int i = t; i < 384; i += 256) in_s[256 + i] = task[b * 384 + i];
    __syncthreads();
    float acc = btf[t];
    for (int i = 0; i < 640; ++i) acc += in_s[i] * Wtf[i * 256 + t];
    ge_s[t] = fmaxf(acc, 0.f);
    __syncthreads();
    if (t < 64) {
        float a2 = bc1[t];
        for (int i = 0; i < 256; ++i) a2 += ge_s[i] * Wc1[i * 64 + t];
        hc_s[t] = fmaxf(a2, 0.f);
    }
    __syncthreads();
    if (t < 64) {
        float v = hc_s[t] * Wc2[t];
#pragma unroll
        for (int off = 32; off >= 1; off >>= 1) v += __shfl_down(v, off);
        if (t == 0) out[b] = v + bc2[0];
    }
}

__global__ __launch_bounds__(256) void zero_kernel(float4* __restrict__ p, int count4)
{
    int i = blockIdx.x * 256 + threadIdx.x;
    if (i < count4) p[i] = make_float4(0.f, 0.f, 0.f, 0.f);
}

extern "C" void kernel_launch(void* const* d_in, const int* in_sizes, int n_in,
                              void* d_out, int out_size, void* d_ws, size_t ws_size,
                              hipStream_t stream)
{
    const float* x      = (const float*)d_in[0];
    const int*   ast    = (const int*)d_in[1];
    const int*   batch  = (const int*)d_in[2];
    const int*   ei[3]  = {(const int*)d_in[3], (const int*)d_in[4], (const int*)d_in[5]};
    const float* task   = (const float*)d_in[6];
    const float* emb    = (const float*)d_in[7];
    const float* Win    = (const float*)d_in[8];
    const float* bin_   = (const float*)d_in[9];
    const float* Wkqv   = (const float*)d_in[10];
    const float* bkqv   = (const float*)d_in[11];
    const float* Wk_rel = (const float*)d_in[12];
    const float* Wv_rel = (const float*)d_in[13];
    const float* p_rel  = (const float*)d_in[14];
    const float* Wout   = (const float*)d_in[15];
    const float* bout   = (const float*)d_in[16];
    const float* skip   = (const float*)d_in[17];
    const float* ln_g   = (const float*)d_in[18];
    const float* ln_b   = (const float*)d_in[19];
    const float* Wtf    = (const float*)d_in[20];
    const float* btf    = (const float*)d_in[21];
    const float* Wc1    = (const float*)d_in[22];
    const float* bc1    = (const float*)d_in[23];
    const float* Wc2    = (const float*)d_in[24];
    const float* bc2    = (const float*)d_in[25];
    float* out = (float*)d_out;
    float* ws  = (float*)d_ws;

    unsigned* hB   = (unsigned*)(ws + OFF_HB);
    unsigned* P0   = (unsigned*)(ws + OFF_P0);   // q -> vt_0 -> vt_2
    unsigned* P1   = (unsigned*)(ws + OFF_P1);   // kt_0 -> kt_1 -> vt_1
    unsigned* AS   = (unsigned*)(ws + OFF_AS);   // kt_2 -> As accumulator
    float*    sbuf = ws + OFF_S;
    int*      rp   = (int*)(ws + OFF_RP);
    int2*     cpair= (int2*)(ws + OFF_CP);
    int*      fill = (int*)(ws + OFF_P0);        // aliases P0 during CSR build only
    float*    Wf   = ws + OFF_WF;
    float*    bf   = ws + OFF_BF;
    int*      bs   = (int*)(ws + OFF_BS);
    float*    psum = ws + OFF_POOL;
    float*    pcnt = psum + (size_t)BB * 256;
    unsigned* WT   = (unsigned*)(ws + OFF_WT);   // 14 gemm slots + 2 Wout slots
    float*    zpart= ws + OFF_IZ;                // [N][4] softmax z01 partial
    unsigned* WinT = (unsigned*)(ws + OFF_WIT);
    unsigned* mxi  = (unsigned*)(ws + OFF_MX);   // [N][4] enc(max)

    fold_weights<<<14, 256, 0, stream>>>(Wkqv, bkqv, Wk_rel, Wv_rel, Wf, bf);
    pack_wt<<<14, 256, 0, stream>>>(Wf, WT);
    pack_wt<<<2, 256, 0, stream>>>(Wout, WT + (size_t)14 * 8192);
    pack_win<<<1, 256, 0, stream>>>(Win, WinT);
    input_proj_mfma<<<NN / 64, 256, 0, stream>>>(x, ast, emb, WinT, bin_, hB);

    zero_kernel<<<(600016 / 4 + 255) / 256, 256, 0, stream>>>((float4*)rp, 600016 / 4);
    zero_kernel<<<(600000 / 4 + 255) / 256, 256, 0, stream>>>((float4*)fill, 600000 / 4);
    csr_hist<<<(3 * EE + 255) / 256, 256, 0, stream>>>(ei[0], ei[1], ei[2], rp);
    scan1<<<dim3(SCAN_NB, 3), 256, 0, stream>>>(rp, bs);
    scan2<<<3, 128, 0, stream>>>(bs);
    scan3<<<dim3(SCAN_NB, 3), 256, 0, stream>>>(rp, bs);
    csr_scatter<<<(3 * EE + 255) / 256, 256, 0, stream>>>(
        ei[0], ei[1], ei[2], rp, fill, cpair);

    const int GG = (NN + 127) / 128;   // 1563 (tail-guarded)
    for (int l = 0; l < 2; ++l) {
        const size_t ls = (size_t)l * 7;   // slots: 0=q, 1..3=kt_r, 4..6=vt_r
        // zero-init softmax max (enc(-inf) = 0)
        zero_kernel<<<(800000 / 4 + 255) / 256, 256, 0, stream>>>((float4*)mxi, 800000 / 4);
        // q -> P0, kt_0 -> P1
        gemm_mfma2<<<GG, 512, 0, stream>>>(
            hB, WT + ls * 8192, bf + ls * 128, P0,
            WT + (ls + 1) * 8192, bf + (ls + 1) * 128, P1);
        edge_scores_csr<<<(EE * 4 + 255) / 256, 256, 0, stream>>>(
            P0, P1, cpair, p_rel + (size_t)l * 12, sbuf, mxi);
        // kt_1 -> P1 (kt_0 consumed), kt_2 -> AS (dead until agg)
        gemm_mfma2<<<GG, 512, 0, stream>>>(
            hB, WT + (ls + 2) * 8192, bf + (ls + 2) * 128, P1,
            WT + (ls + 3) * 8192, bf + (ls + 3) * 128, AS);
        edge_scores_csr<<<(EE * 4 + 255) / 256, 256, 0, stream>>>(
            P0, P1, cpair + (size_t)EE,
            p_rel + (size_t)(l * 3 + 1) * 4, sbuf + (size_t)EE * 4, mxi);
        edge_scores_csr<<<(EE * 4 + 255) / 256, 256, 0, stream>>>(
            P0, AS, cpair + (size_t)2 * EE,
            p_rel + (size_t)(l * 3 + 2) * 4, sbuf + (size_t)2 * EE * 4, mxi);
        // vt_0 -> P0 (q dead), vt_1 -> P1  (softmax fused into agg: R17)
        gemm_mfma2<<<GG, 512, 0, stream>>>(
            hB, WT + (ls + 4) * 8192, bf + (ls + 4) * 128, P0,
            WT + (ls + 5) * 8192, bf + (ls + 5) * 128, P1);
        agg_reg<2, 1><<<NN / 16, 256, 0, stream>>>(P0, P1, sbuf, rp, cpair, 0, 1, mxi, zpart, AS);
        gemm_mfma<<<GG, 512, 0, stream>>>(hB, WT + (ls + 6) * 8192, bf + (ls + 6) * 128, P0);
        agg_reg<1, 0><<<NN / 16, 256, 0, stream>>>(P0, P0, sbuf, rp, cpair, 2, 2, mxi, zpart, AS);
        out_ln<<<GG, 512, 0, stream>>>(
            AS, hB, WT + (size_t)(14 + l) * 8192, bout + (size_t)l * 128,
            skip + l, ln_g + (size_t)l * 128, ln_b + (size_t)l * 128);
    }

    zero_kernel<<<(16512 / 4 + 255) / 256, 256, 0, stream>>>((float4*)psum, 16512 / 4);
    pool_graph<<<BB * 8, 256, 0, stream>>>(hB, x, batch, psum, pcnt);
    head_kernel<<<BB, 256, 0, stream>>>(psum, pcnt, task, Wtf, btf, Wc1, bc1, Wc2, bc2, out);
}